// Round 1
// baseline (142.532 us; speedup 1.0000x reference)
//
#include <hip/hip_runtime.h>

#define TOT     2048      // B*SEQ rows
#define INDIM   512
#define OD      256
#define SEQL    1024
#define TQ      512       // out_seq
#define NB      2
#define LN_EPS  1e-5f

// ---------------- K1: Z = x @ M^T, Zn = LayerNorm(Z) ----------------
// 8 rows per block, 256 threads (thread = output column).
// x rows read via wave-uniform addresses -> scalar loads; M rows per-thread from L2.
__global__ __launch_bounds__(256) void k1_gemm_ln(
    const float* __restrict__ x, const float* __restrict__ M,
    const float* __restrict__ gamma, const float* __restrict__ beta,
    float* __restrict__ Z, float* __restrict__ Zn)
{
    const int r0 = blockIdx.x * 8;
    const int c  = threadIdx.x;

    float acc[8];
#pragma unroll
    for (int r = 0; r < 8; ++r) acc[r] = 0.f;

    const float* Mr = M + c * INDIM;
    for (int k = 0; k < INDIM; k += 8) {
        float4 m0 = *(const float4*)(Mr + k);
        float4 m1 = *(const float4*)(Mr + k + 4);
#pragma unroll
        for (int r = 0; r < 8; ++r) {
            float4 x0 = *(const float4*)(x + (r0 + r) * INDIM + k);      // uniform -> s_load
            float4 x1 = *(const float4*)(x + (r0 + r) * INDIM + k + 4);  // uniform -> s_load
            acc[r] += x0.x*m0.x + x0.y*m0.y + x0.z*m0.z + x0.w*m0.w
                    + x1.x*m1.x + x1.y*m1.y + x1.z*m1.z + x1.w*m1.w;
        }
    }

    __shared__ float s1[8][4], s2[8][4];
    const int lane = threadIdx.x & 63;
    const int wid  = threadIdx.x >> 6;
#pragma unroll
    for (int r = 0; r < 8; ++r) {
        float s = acc[r], q = acc[r] * acc[r];
#pragma unroll
        for (int off = 32; off > 0; off >>= 1) {
            s += __shfl_xor(s, off, 64);
            q += __shfl_xor(q, off, 64);
        }
        if (lane == 0) { s1[r][wid] = s; s2[r][wid] = q; }
    }
    __syncthreads();
#pragma unroll
    for (int r = 0; r < 8; ++r) {
        float s  = s1[r][0] + s1[r][1] + s1[r][2] + s1[r][3];
        float q  = s2[r][0] + s2[r][1] + s2[r][2] + s2[r][3];
        float mu = s * (1.f / OD);
        float var = q * (1.f / OD) - mu * mu;
        float inv = rsqrtf(var + LN_EPS);
        float z  = acc[r];
        float zn = (z - mu) * inv * gamma[c] + beta[c];
        Z [(r0 + r) * OD + c] = z;
        Zn[(r0 + r) * OD + c] = zn;
    }
}

// ---------------- K2: T[k,i] = sum_j Zn[k,j]*P[i,j]*cos(2*pi*k/(i*256+j+2)) ----
// Block: 64 threads, tile 32k x 32i, j-chunk of 64 (blockIdx.z = j-split of 4).
// Thread: 4k x 4i register tile; per 4-j step: 8 ds_read_b128 + 16 rcp + 64 cos.
// Writes partial plane Tp[blockIdx.z] (no atomics -> deterministic).
__global__ __launch_bounds__(64) void k2_t(
    const float* __restrict__ Zn, const float* __restrict__ P,
    float* __restrict__ Tp)
{
    const int k0 = blockIdx.x * 32;
    const int i0 = blockIdx.y * 32;
    const int j0 = blockIdx.z * 64;

    __shared__ float zt[32][68];   // +4 pad: breaks 64-word row stride (32-way -> ~4-way)
    __shared__ float pt[32][68];

    const int tid = threadIdx.x;
    for (int m = tid; m < 512; m += 64) {
        const int row = m >> 4;
        const int c4  = (m & 15) << 2;
        *(float4*)&zt[row][c4] = *(const float4*)(Zn + (k0 + row) * OD + j0 + c4);
        *(float4*)&pt[row][c4] = *(const float4*)(P  + (i0 + row) * OD + j0 + c4);
    }
    __syncthreads();

    const int tk = tid & 7;
    const int ti = tid >> 3;
    const int kb = k0 + tk * 4;
    const int ib = i0 + ti * 4;

    float kf[4];
#pragma unroll
    for (int r = 0; r < 4; ++r) kf[r] = (float)(kb + r);

    float acc[4][4];
#pragma unroll
    for (int r = 0; r < 4; ++r)
#pragma unroll
        for (int cc = 0; cc < 4; ++cc) acc[r][cc] = 0.f;

    for (int q = 0; q < 16; ++q) {
        const int j = q * 4;
        float4 zv[4], pv[4];
#pragma unroll
        for (int r = 0; r < 4; ++r)  zv[r]  = *(const float4*)&zt[tk * 4 + r][j];
#pragma unroll
        for (int cc = 0; cc < 4; ++cc) pv[cc] = *(const float4*)&pt[ti * 4 + cc][j];

#pragma unroll
        for (int cc = 0; cc < 4; ++cc) {
            const float pb = (float)((ib + cc) * OD + j0 + j + 2);   // exact (< 2^24)
            const float ip0 = __builtin_amdgcn_rcpf(pb);
            const float ip1 = __builtin_amdgcn_rcpf(pb + 1.f);
            const float ip2 = __builtin_amdgcn_rcpf(pb + 2.f);
            const float ip3 = __builtin_amdgcn_rcpf(pb + 3.f);
#pragma unroll
            for (int r = 0; r < 4; ++r) {
                // v_cos_f32 input is in revolutions: cos(2*pi*f)
                const float f0 = __builtin_amdgcn_fractf(kf[r] * ip0);
                const float f1 = __builtin_amdgcn_fractf(kf[r] * ip1);
                const float f2 = __builtin_amdgcn_fractf(kf[r] * ip2);
                const float f3 = __builtin_amdgcn_fractf(kf[r] * ip3);
                const float c0 = __builtin_amdgcn_cosf(f0);
                const float c1 = __builtin_amdgcn_cosf(f1);
                const float c2 = __builtin_amdgcn_cosf(f2);
                const float c3 = __builtin_amdgcn_cosf(f3);
                acc[r][cc] += zv[r].x * pv[cc].x * c0
                            + zv[r].y * pv[cc].y * c1
                            + zv[r].z * pv[cc].z * c2
                            + zv[r].w * pv[cc].w * c3;
            }
        }
    }

    float* Tpl = Tp + blockIdx.z * (TOT * OD);
#pragma unroll
    for (int r = 0; r < 4; ++r) {
        float4 v = make_float4(acc[r][0], acc[r][1], acc[r][2], acc[r][3]);
        *(float4*)(Tpl + (kb + r) * OD + ib) = v;
    }
}

// ---------------- K2b: W = Z + sum(Tp planes), in place over Z; write out_seq scalar ---
__global__ __launch_bounds__(256) void k2b_comb(
    float* __restrict__ ZW, const float* __restrict__ Tp,
    float* __restrict__ out, int out_size)
{
    const int m = blockIdx.x * 256 + threadIdx.x;   // float4 index
    const int N4 = (TOT * OD) / 4;
    if (m < N4) {
        float4 z = ((const float4*)ZW)[m];
#pragma unroll
        for (int p = 0; p < 4; ++p) {
            float4 t = ((const float4*)(Tp + p * (TOT * OD)))[m];
            z.x += t.x; z.y += t.y; z.z += t.z; z.w += t.w;
        }
        ((float4*)ZW)[m] = z;
    }
    if (m == 0 && out_size > NB * TQ * OD)
        out[NB * TQ * OD] = (float)TQ;   // second output: out_seq = 512
}

// ---------------- K3: out[b,t,o] = sum_s W[b*SEQ+s, o] * L[s, t] ----------------
// Block: 256 threads (o = tid), 8 t's, 512-s half (blockIdx.y). AL via uniform s_loads.
// Two atomic adds per slot from zero -> commutative -> bit-deterministic.
__global__ __launch_bounds__(256) void k3_link(
    const float* __restrict__ W, const float* __restrict__ L,
    float* __restrict__ out)
{
    const int t0 = blockIdx.x * 8;
    const int s0 = blockIdx.y * 512;
    const int b  = blockIdx.z;
    const int o  = threadIdx.x;

    const float* Wb = W + (size_t)b * SEQL * OD + o;
    float acc[8];
#pragma unroll
    for (int t = 0; t < 8; ++t) acc[t] = 0.f;

    for (int s = s0; s < s0 + 512; s += 2) {
        const float w0 = Wb[s * OD];
        const float w1 = Wb[(s + 1) * OD];
        const float* al0 = L + s * TQ + t0;          // uniform -> s_load
        const float* al1 = al0 + TQ;
#pragma unroll
        for (int t = 0; t < 8; ++t)
            acc[t] += w0 * al0[t] + w1 * al1[t];
    }

    float* ob = out + ((size_t)(b * TQ + t0)) * OD + o;
#pragma unroll
    for (int t = 0; t < 8; ++t)
        atomicAdd(ob + t * OD, acc[t]);
}

extern "C" void kernel_launch(void* const* d_in, const int* in_sizes, int n_in,
                              void* d_out, int out_size, void* d_ws, size_t ws_size,
                              hipStream_t stream)
{
    const float* x  = (const float*)d_in[0];
    const float* M  = (const float*)d_in[1];
    const float* P  = (const float*)d_in[2];
    const float* L  = (const float*)d_in[3];
    const float* g  = (const float*)d_in[4];
    const float* be = (const float*)d_in[5];
    float* out = (float*)d_out;
    float* ws  = (float*)d_ws;

    float* Z  = ws;                    // [TOT*OD]; becomes W after k2b
    float* Zn = ws + TOT * OD;         // [TOT*OD]
    float* Tp = ws + 2 * TOT * OD;     // 4 planes of [TOT*OD]  (total ws: 12 MB)

    // zero the main output (atomics accumulate into it)
    hipMemsetAsync(d_out, 0, (size_t)(NB * TQ * OD) * sizeof(float), stream);

    k1_gemm_ln<<<TOT / 8, 256, 0, stream>>>(x, M, g, be, Z, Zn);
    k2_t<<<dim3(TOT / 32, OD / 32, 4), 64, 0, stream>>>(Zn, P, Tp);
    k2b_comb<<<(TOT * OD / 4 + 255) / 256, 256, 0, stream>>>(Z, Tp, out, out_size);
    k3_link<<<dim3(TQ / 8, 2, NB), 256, 0, stream>>>(Z, L, out);
}

// Round 6
// 119.166 us; speedup vs baseline: 1.1961x; 1.1961x over previous
//
#include <hip/hip_runtime.h>

#define TOT     2048      // B*SEQ rows
#define INDIM   512
#define OD      256
#define SEQL    1024
#define TQ      512       // out_seq
#define NB      2
#define LN_EPS  1e-5f

#define SSPLIT  8
#define SCHUNK  (SEQL / SSPLIT)   // 128
#define TPB     16                // t's per block (2 halves of 8)

// ---------------- K1: Z = x @ M^T, Zn = LayerNorm(Z) ----------------
__global__ __launch_bounds__(256) void k1_gemm_ln(
    const float* __restrict__ x, const float* __restrict__ M,
    const float* __restrict__ gamma, const float* __restrict__ beta,
    float* __restrict__ Z, float* __restrict__ Zn)
{
    const int r0 = blockIdx.x * 8;
    const int c  = threadIdx.x;

    float acc[8];
#pragma unroll
    for (int r = 0; r < 8; ++r) acc[r] = 0.f;

    const float* Mr = M + c * INDIM;
    for (int k = 0; k < INDIM; k += 8) {
        float4 m0 = *(const float4*)(Mr + k);
        float4 m1 = *(const float4*)(Mr + k + 4);
#pragma unroll
        for (int r = 0; r < 8; ++r) {
            float4 x0 = *(const float4*)(x + (r0 + r) * INDIM + k);      // uniform -> s_load
            float4 x1 = *(const float4*)(x + (r0 + r) * INDIM + k + 4);  // uniform -> s_load
            acc[r] += x0.x*m0.x + x0.y*m0.y + x0.z*m0.z + x0.w*m0.w
                    + x1.x*m1.x + x1.y*m1.y + x1.z*m1.z + x1.w*m1.w;
        }
    }

    __shared__ float s1[8][4], s2[8][4];
    const int lane = threadIdx.x & 63;
    const int wid  = threadIdx.x >> 6;
#pragma unroll
    for (int r = 0; r < 8; ++r) {
        float s = acc[r], q = acc[r] * acc[r];
#pragma unroll
        for (int off = 32; off > 0; off >>= 1) {
            s += __shfl_xor(s, off, 64);
            q += __shfl_xor(q, off, 64);
        }
        if (lane == 0) { s1[r][wid] = s; s2[r][wid] = q; }
    }
    __syncthreads();
#pragma unroll
    for (int r = 0; r < 8; ++r) {
        float s  = s1[r][0] + s1[r][1] + s1[r][2] + s1[r][3];
        float q  = s2[r][0] + s2[r][1] + s2[r][2] + s2[r][3];
        float mu = s * (1.f / OD);
        float var = q * (1.f / OD) - mu * mu;
        float inv = rsqrtf(var + LN_EPS);
        float z  = acc[r];
        float zn = (z - mu) * inv * gamma[c] + beta[c];
        Z [(r0 + r) * OD + c] = z;
        Zn[(r0 + r) * OD + c] = zn;
    }
}

// ---------------- K2: T[k,i] = sum_j Zn[k,j]*P[i,j]*cos(2*pi*k/(i*256+j+2)) ----
__global__ __launch_bounds__(64) void k2_t(
    const float* __restrict__ Zn, const float* __restrict__ P,
    float* __restrict__ Tp)
{
    const int k0 = blockIdx.x * 32;
    const int i0 = blockIdx.y * 32;
    const int j0 = blockIdx.z * 64;

    __shared__ float zt[32][68];
    __shared__ float pt[32][68];

    const int tid = threadIdx.x;
    for (int m = tid; m < 512; m += 64) {
        const int row = m >> 4;
        const int c4  = (m & 15) << 2;
        *(float4*)&zt[row][c4] = *(const float4*)(Zn + (k0 + row) * OD + j0 + c4);
        *(float4*)&pt[row][c4] = *(const float4*)(P  + (i0 + row) * OD + j0 + c4);
    }
    __syncthreads();

    const int tk = tid & 7;
    const int ti = tid >> 3;
    const int kb = k0 + tk * 4;
    const int ib = i0 + ti * 4;

    float kf[4];
#pragma unroll
    for (int r = 0; r < 4; ++r) kf[r] = (float)(kb + r);

    float acc[4][4];
#pragma unroll
    for (int r = 0; r < 4; ++r)
#pragma unroll
        for (int cc = 0; cc < 4; ++cc) acc[r][cc] = 0.f;

    for (int q = 0; q < 16; ++q) {
        const int j = q * 4;
        float4 zv[4], pv[4];
#pragma unroll
        for (int r = 0; r < 4; ++r)  zv[r]  = *(const float4*)&zt[tk * 4 + r][j];
#pragma unroll
        for (int cc = 0; cc < 4; ++cc) pv[cc] = *(const float4*)&pt[ti * 4 + cc][j];

#pragma unroll
        for (int cc = 0; cc < 4; ++cc) {
            const float pb = (float)((ib + cc) * OD + j0 + j + 2);   // exact (< 2^24)
            const float ip0 = __builtin_amdgcn_rcpf(pb);
            const float ip1 = __builtin_amdgcn_rcpf(pb + 1.f);
            const float ip2 = __builtin_amdgcn_rcpf(pb + 2.f);
            const float ip3 = __builtin_amdgcn_rcpf(pb + 3.f);
#pragma unroll
            for (int r = 0; r < 4; ++r) {
                const float f0 = __builtin_amdgcn_fractf(kf[r] * ip0);
                const float f1 = __builtin_amdgcn_fractf(kf[r] * ip1);
                const float f2 = __builtin_amdgcn_fractf(kf[r] * ip2);
                const float f3 = __builtin_amdgcn_fractf(kf[r] * ip3);
                const float c0 = __builtin_amdgcn_cosf(f0);
                const float c1 = __builtin_amdgcn_cosf(f1);
                const float c2 = __builtin_amdgcn_cosf(f2);
                const float c3 = __builtin_amdgcn_cosf(f3);
                acc[r][cc] += zv[r].x * pv[cc].x * c0
                            + zv[r].y * pv[cc].y * c1
                            + zv[r].z * pv[cc].z * c2
                            + zv[r].w * pv[cc].w * c3;
            }
        }
    }

    float* Tpl = Tp + blockIdx.z * (TOT * OD);
#pragma unroll
    for (int r = 0; r < 4; ++r) {
        float4 v = make_float4(acc[r][0], acc[r][1], acc[r][2], acc[r][3]);
        *(float4*)(Tpl + (kb + r) * OD + ib) = v;
    }
}

// ---------------- K2b: W = Z + sum(Tp planes), in place over Z ----------------
__global__ __launch_bounds__(256) void k2b_comb(
    float* __restrict__ ZW, const float* __restrict__ Tp)
{
    const int m = blockIdx.x * 256 + threadIdx.x;   // float4 index
    const int N4 = (TOT * OD) / 4;
    if (m < N4) {
        float4 z = ((const float4*)ZW)[m];
#pragma unroll
        for (int p = 0; p < 4; ++p) {
            float4 t = ((const float4*)(Tp + p * (TOT * OD)))[m];
            z.x += t.x; z.y += t.y; z.z += t.z; z.w += t.w;
        }
        ((float4*)ZW)[m] = z;
    }
}

// ---------------- K3: partial[p][b,t,o] = sum_{s in chunk p} W[b,s,o]*L[s,t] ----
// Block (256,2): tid.x = o, tid.y = t-half. Grid (TQ/16, 8, NB) = 512 blocks
// -> 16 waves/CU. s unrolled x4: 4 w-loads in flight, 8 independent acc chains.
__global__ __launch_bounds__(512) void k3_link(
    const float* __restrict__ W, const float* __restrict__ L,
    float* __restrict__ part)
{
    const int t0 = blockIdx.x * TPB + threadIdx.y * 8;
    const int s0 = blockIdx.y * SCHUNK;
    const int b  = blockIdx.z;
    const int o  = threadIdx.x;

    const float* Wb = W + (size_t)b * SEQL * OD + o;
    float acc[8];
#pragma unroll
    for (int t = 0; t < 8; ++t) acc[t] = 0.f;

    for (int s = s0; s < s0 + SCHUNK; s += 4) {
        const float w0 = Wb[(s + 0) * OD];
        const float w1 = Wb[(s + 1) * OD];
        const float w2 = Wb[(s + 2) * OD];
        const float w3 = Wb[(s + 3) * OD];
        const float* l0 = L + (s + 0) * TQ + t0;   // uniform -> s_load
        const float* l1 = l0 + TQ;
        const float* l2 = l1 + TQ;
        const float* l3 = l2 + TQ;
#pragma unroll
        for (int t = 0; t < 8; ++t)
            acc[t] += w0 * l0[t] + w1 * l1[t] + w2 * l2[t] + w3 * l3[t];
    }

    float* pb = part + (size_t)blockIdx.y * (NB * TQ * OD)
                     + ((size_t)(b * TQ + t0)) * OD + o;
#pragma unroll
    for (int t = 0; t < 8; ++t)
        pb[t * OD] = acc[t];
}

// ---------------- K4: out = sum of 8 partial planes; also write out_seq ------
__global__ __launch_bounds__(256) void k4_comb(
    const float* __restrict__ part, float* __restrict__ out, int out_size)
{
    const int m = blockIdx.x * 256 + threadIdx.x;   // float4 index
    const int N4 = (NB * TQ * OD) / 4;              // 65536
    if (m < N4) {
        float4 a = ((const float4*)part)[m];
#pragma unroll
        for (int p = 1; p < SSPLIT; ++p) {
            float4 t = ((const float4*)(part + (size_t)p * (NB * TQ * OD)))[m];
            a.x += t.x; a.y += t.y; a.z += t.z; a.w += t.w;
        }
        ((float4*)out)[m] = a;
    }
    if (m == 0 && out_size > NB * TQ * OD)
        out[NB * TQ * OD] = (float)TQ;   // second output: out_seq = 512
}

extern "C" void kernel_launch(void* const* d_in, const int* in_sizes, int n_in,
                              void* d_out, int out_size, void* d_ws, size_t ws_size,
                              hipStream_t stream)
{
    const float* x  = (const float*)d_in[0];
    const float* M  = (const float*)d_in[1];
    const float* P  = (const float*)d_in[2];
    const float* L  = (const float*)d_in[3];
    const float* g  = (const float*)d_in[4];
    const float* be = (const float*)d_in[5];
    float* out = (float*)d_out;
    float* ws  = (float*)d_ws;

    float* Z    = ws;                    // [TOT*OD]; becomes W after k2b
    float* Zn   = ws + TOT * OD;         // [TOT*OD]
    float* Tp   = ws + 2 * TOT * OD;     // 4 planes of [TOT*OD] (8 MB)
    float* part = Tp;                    // reuse Tp region after k2b: 8 x 1 MB

    k1_gemm_ln<<<TOT / 8, 256, 0, stream>>>(x, M, g, be, Z, Zn);
    k2_t<<<dim3(TOT / 32, OD / 32, 4), 64, 0, stream>>>(Zn, P, Tp);
    k2b_comb<<<(TOT * OD / 4 + 255) / 256, 256, 0, stream>>>(Z, Tp);
    k3_link<<<dim3(TQ / TPB, SSPLIT, NB), dim3(256, 2), 0, stream>>>(Z, L, part);
    k4_comb<<<(NB * TQ * OD / 4 + 255) / 256, 256, 0, stream>>>(part, out, out_size);
}

// Round 7
// 92.531 us; speedup vs baseline: 1.5404x; 1.2879x over previous
//
#include <hip/hip_runtime.h>

#define TOT     2048      // B*SEQ rows
#define INDIM   512
#define OD      256
#define SEQL    1024
#define TQ      512       // out_seq
#define NB      2
#define LN_EPS  1e-5f

#define SSPLIT  8                 // k3 s-split (must match k4)
#define K3T     8                 // t's per k3 block
#define K3CH    (SEQL / SSPLIT)   // 128 s per k3 block
#define K3SUB   16                // s per LDS stage

// ---------------- K1: Z = x @ M^T, Zn = LayerNorm(Z) ----------------
// Block (256,4): tid.x = output column c, tid.y = k-quarter (K=128 each).
// M staged coalesced into dbuf LDS (stride 9 -> 2-way alias, free); x via
// wave-uniform s_loads. 256 blocks x 16 waves, 2 blocks/CU -> 8 waves/SIMD.
__global__ __launch_bounds__(1024, 8) void k1_gemm_ln(
    const float* __restrict__ x, const float* __restrict__ M,
    const float* __restrict__ gamma, const float* __restrict__ beta,
    float* __restrict__ Z, float* __restrict__ Zn)
{
    const int r0 = blockIdx.x * 8;
    const int c  = threadIdx.x;                                      // 0..255
    const int ty = __builtin_amdgcn_readfirstlane(threadIdx.y);      // 0..3 (wave-uniform)

    __shared__ float Mt[4][2][256][9];   // 72 KB double-buffered M tiles
    __shared__ float s1[8][4], s2[8][4];

    const int kb0 = ty * 128;

    float acc[8];
#pragma unroll
    for (int r = 0; r < 8; ++r) acc[r] = 0.f;

    // stage chunk 0
#pragma unroll
    for (int p = 0; p < 2; ++p) {
        const int f = c + p * 256;
        const int row = f >> 1, kq = (f & 1) * 4;
        float4 v = *(const float4*)(M + row * INDIM + kb0 + kq);
        Mt[ty][0][row][kq + 0] = v.x; Mt[ty][0][row][kq + 1] = v.y;
        Mt[ty][0][row][kq + 2] = v.z; Mt[ty][0][row][kq + 3] = v.w;
    }
    __syncthreads();

    for (int ch = 0; ch < 16; ++ch) {
        const int buf = ch & 1;
        if (ch + 1 < 16) {                       // prefetch next chunk into other buffer
            const int kb = kb0 + (ch + 1) * 8;
#pragma unroll
            for (int p = 0; p < 2; ++p) {
                const int f = c + p * 256;
                const int row = f >> 1, kq = (f & 1) * 4;
                float4 v = *(const float4*)(M + row * INDIM + kb + kq);
                Mt[ty][buf ^ 1][row][kq + 0] = v.x; Mt[ty][buf ^ 1][row][kq + 1] = v.y;
                Mt[ty][buf ^ 1][row][kq + 2] = v.z; Mt[ty][buf ^ 1][row][kq + 3] = v.w;
            }
        }
        const int kb = kb0 + ch * 8;
#pragma unroll
        for (int kk = 0; kk < 8; ++kk) {
            const float m = Mt[ty][buf][c][kk];
#pragma unroll
            for (int r = 0; r < 8; ++r)
                acc[r] += m * x[(r0 + r) * INDIM + kb + kk];   // uniform -> s_load
        }
        __syncthreads();
    }

    // combine the 4 k-quarters; comb overlays Mt (no longer read)
    float* comb = &Mt[0][0][0][0];               // need 3*8*256 floats, have 18432
    if (ty > 0) {
#pragma unroll
        for (int r = 0; r < 8; ++r)
            comb[((ty - 1) * 8 + r) * 256 + c] = acc[r];
    }
    __syncthreads();

    const int lane = c & 63;
    const int wid  = c >> 6;
    if (ty == 0) {
#pragma unroll
        for (int r = 0; r < 8; ++r)
            acc[r] += comb[r * 256 + c] + comb[(8 + r) * 256 + c] + comb[(16 + r) * 256 + c];
#pragma unroll
        for (int r = 0; r < 8; ++r) {
            float s = acc[r], q = acc[r] * acc[r];
#pragma unroll
            for (int off = 32; off > 0; off >>= 1) {
                s += __shfl_xor(s, off, 64);
                q += __shfl_xor(q, off, 64);
            }
            if (lane == 0) { s1[r][wid] = s; s2[r][wid] = q; }
        }
    }
    __syncthreads();
    if (ty == 0) {
#pragma unroll
        for (int r = 0; r < 8; ++r) {
            float s  = s1[r][0] + s1[r][1] + s1[r][2] + s1[r][3];
            float q  = s2[r][0] + s2[r][1] + s2[r][2] + s2[r][3];
            float mu = s * (1.f / OD);
            float var = q * (1.f / OD) - mu * mu;
            float inv = rsqrtf(var + LN_EPS);
            float z  = acc[r];
            float zn = (z - mu) * inv * gamma[c] + beta[c];
            Z [(r0 + r) * OD + c] = z;
            Zn[(r0 + r) * OD + c] = zn;
        }
    }
}

// ---------------- K2: T[k,i] = sum_j Zn[k,j]*P[i,j]*cos(2*pi*k/(i*256+j+2)) ----
// (unchanged this round — measure it as top dispatch, optimize next)
__global__ __launch_bounds__(64) void k2_t(
    const float* __restrict__ Zn, const float* __restrict__ P,
    float* __restrict__ Tp)
{
    const int k0 = blockIdx.x * 32;
    const int i0 = blockIdx.y * 32;
    const int j0 = blockIdx.z * 64;

    __shared__ float zt[32][68];
    __shared__ float pt[32][68];

    const int tid = threadIdx.x;
    for (int m = tid; m < 512; m += 64) {
        const int row = m >> 4;
        const int c4  = (m & 15) << 2;
        *(float4*)&zt[row][c4] = *(const float4*)(Zn + (k0 + row) * OD + j0 + c4);
        *(float4*)&pt[row][c4] = *(const float4*)(P  + (i0 + row) * OD + j0 + c4);
    }
    __syncthreads();

    const int tk = tid & 7;
    const int ti = tid >> 3;
    const int kb = k0 + tk * 4;
    const int ib = i0 + ti * 4;

    float kf[4];
#pragma unroll
    for (int r = 0; r < 4; ++r) kf[r] = (float)(kb + r);

    float acc[4][4];
#pragma unroll
    for (int r = 0; r < 4; ++r)
#pragma unroll
        for (int cc = 0; cc < 4; ++cc) acc[r][cc] = 0.f;

    for (int q = 0; q < 16; ++q) {
        const int j = q * 4;
        float4 zv[4], pv[4];
#pragma unroll
        for (int r = 0; r < 4; ++r)  zv[r]  = *(const float4*)&zt[tk * 4 + r][j];
#pragma unroll
        for (int cc = 0; cc < 4; ++cc) pv[cc] = *(const float4*)&pt[ti * 4 + cc][j];

#pragma unroll
        for (int cc = 0; cc < 4; ++cc) {
            const float pb = (float)((ib + cc) * OD + j0 + j + 2);   // exact (< 2^24)
            const float ip0 = __builtin_amdgcn_rcpf(pb);
            const float ip1 = __builtin_amdgcn_rcpf(pb + 1.f);
            const float ip2 = __builtin_amdgcn_rcpf(pb + 2.f);
            const float ip3 = __builtin_amdgcn_rcpf(pb + 3.f);
#pragma unroll
            for (int r = 0; r < 4; ++r) {
                const float f0 = __builtin_amdgcn_fractf(kf[r] * ip0);
                const float f1 = __builtin_amdgcn_fractf(kf[r] * ip1);
                const float f2 = __builtin_amdgcn_fractf(kf[r] * ip2);
                const float f3 = __builtin_amdgcn_fractf(kf[r] * ip3);
                const float c0 = __builtin_amdgcn_cosf(f0);
                const float c1 = __builtin_amdgcn_cosf(f1);
                const float c2 = __builtin_amdgcn_cosf(f2);
                const float c3 = __builtin_amdgcn_cosf(f3);
                acc[r][cc] += zv[r].x * pv[cc].x * c0
                            + zv[r].y * pv[cc].y * c1
                            + zv[r].z * pv[cc].z * c2
                            + zv[r].w * pv[cc].w * c3;
            }
        }
    }

    float* Tpl = Tp + blockIdx.z * (TOT * OD);
#pragma unroll
    for (int r = 0; r < 4; ++r) {
        float4 v = make_float4(acc[r][0], acc[r][1], acc[r][2], acc[r][3]);
        *(float4*)(Tpl + (kb + r) * OD + ib) = v;
    }
}

// ---------------- K2b: W = Z + sum(Tp planes), in place over Z ----------------
__global__ __launch_bounds__(256) void k2b_comb(
    float* __restrict__ ZW, const float* __restrict__ Tp)
{
    const int m = blockIdx.x * 256 + threadIdx.x;   // float4 index
    const int N4 = (TOT * OD) / 4;
    if (m < N4) {
        float4 z = ((const float4*)ZW)[m];
#pragma unroll
        for (int p = 0; p < 4; ++p) {
            float4 t = ((const float4*)(Tp + p * (TOT * OD)))[m];
            z.x += t.x; z.y += t.y; z.z += t.z; z.w += t.w;
        }
        ((float4*)ZW)[m] = z;
    }
}

// ---------------- K3: partial[p][b,t,o] = sum_{s in chunk p} W[b,s,o]*L[s,t] ----
// Block 256 (o = tid), 8 t's, 128-s chunk staged via dbuf LDS (16 s x 256 o).
// W from LDS lane-stride-1 (conflict-free), L via uniform s_load_dwordx8.
// Grid (64,8,2) = 1024 blocks -> 4 blocks/CU -> 4 waves/SIMD.
__global__ __launch_bounds__(256, 4) void k3_link(
    const float* __restrict__ W, const float* __restrict__ L,
    float* __restrict__ part)
{
    const int t0 = blockIdx.x * K3T;
    const int p  = blockIdx.y;
    const int b  = blockIdx.z;
    const int s0 = p * K3CH;
    const int o  = threadIdx.x;

    __shared__ float Ws[2][K3SUB][256];          // 32 KB double-buffered W tiles

    const float* Wb = W + ((size_t)b * SEQL + s0) * OD;

    float acc[K3T];
#pragma unroll
    for (int t = 0; t < K3T; ++t) acc[t] = 0.f;

    // stage sub-chunk 0 (perfectly coalesced: 64 lanes cover one 1KB row)
#pragma unroll
    for (int qq = 0; qq < 4; ++qq) {
        const int f = o + qq * 256;
        const int row = f >> 6, c4 = (f & 63) * 4;
        *(float4*)&Ws[0][row][c4] = *(const float4*)(Wb + row * OD + c4);
    }
    __syncthreads();

    for (int sub = 0; sub < K3CH / K3SUB; ++sub) {   // 8 sub-chunks
        const int buf = sub & 1;
        if (sub + 1 < K3CH / K3SUB) {
            const float* src = Wb + (sub + 1) * K3SUB * OD;
#pragma unroll
            for (int qq = 0; qq < 4; ++qq) {
                const int f = o + qq * 256;
                const int row = f >> 6, c4 = (f & 63) * 4;
                *(float4*)&Ws[buf ^ 1][row][c4] = *(const float4*)(src + row * OD + c4);
            }
        }
        const int sbase = s0 + sub * K3SUB;
#pragma unroll
        for (int sp = 0; sp < K3SUB; ++sp) {
            const float w = Ws[buf][sp][o];
            const float* lr = L + (size_t)(sbase + sp) * TQ + t0;   // uniform -> s_load
#pragma unroll
            for (int t = 0; t < K3T; ++t)
                acc[t] += w * lr[t];
        }
        __syncthreads();
    }

    float* pb = part + (size_t)p * (NB * TQ * OD)
                     + ((size_t)(b * TQ + t0)) * OD + o;
#pragma unroll
    for (int t = 0; t < K3T; ++t)
        pb[t * OD] = acc[t];
}

// ---------------- K4: out = sum of 8 partial planes; also write out_seq ------
__global__ __launch_bounds__(256) void k4_comb(
    const float* __restrict__ part, float* __restrict__ out, int out_size)
{
    const int m = blockIdx.x * 256 + threadIdx.x;   // float4 index
    const int N4 = (NB * TQ * OD) / 4;              // 65536
    if (m < N4) {
        float4 a = ((const float4*)part)[m];
#pragma unroll
        for (int p = 1; p < SSPLIT; ++p) {
            float4 t = ((const float4*)(part + (size_t)p * (NB * TQ * OD)))[m];
            a.x += t.x; a.y += t.y; a.z += t.z; a.w += t.w;
        }
        ((float4*)out)[m] = a;
    }
    if (m == 0 && out_size > NB * TQ * OD)
        out[NB * TQ * OD] = (float)TQ;   // second output: out_seq = 512
}

extern "C" void kernel_launch(void* const* d_in, const int* in_sizes, int n_in,
                              void* d_out, int out_size, void* d_ws, size_t ws_size,
                              hipStream_t stream)
{
    const float* x  = (const float*)d_in[0];
    const float* M  = (const float*)d_in[1];
    const float* P  = (const float*)d_in[2];
    const float* L  = (const float*)d_in[3];
    const float* g  = (const float*)d_in[4];
    const float* be = (const float*)d_in[5];
    float* out = (float*)d_out;
    float* ws  = (float*)d_ws;

    float* Z    = ws;                    // [TOT*OD]; becomes W after k2b
    float* Zn   = ws + TOT * OD;         // [TOT*OD]
    float* Tp   = ws + 2 * TOT * OD;     // 4 planes of [TOT*OD] (8 MB)
    float* part = Tp;                    // reuse Tp region after k2b: 8 x 1 MB

    k1_gemm_ln<<<TOT / 8, dim3(256, 4), 0, stream>>>(x, M, g, be, Z, Zn);
    k2_t<<<dim3(TOT / 32, OD / 32, 4), 64, 0, stream>>>(Zn, P, Tp);
    k2b_comb<<<(TOT * OD / 4 + 255) / 256, 256, 0, stream>>>(Z, Tp);
    k3_link<<<dim3(TQ / K3T, SSPLIT, NB), 256, 0, stream>>>(Z, L, part);
    k4_comb<<<(NB * TQ * OD / 4 + 255) / 256, 256, 0, stream>>>(part, out, out_size);
}

// Round 8
// 61.357 us; speedup vs baseline: 2.3230x; 1.5081x over previous
//
#include <hip/hip_runtime.h>
#include <hip/hip_bf16.h>

#define TOT     2048      // B*SEQ rows
#define INDIM   512
#define OD      256
#define SEQL    1024
#define TQ      512       // out_seq
#define NB      2
#define LN_EPS  1e-5f

#define JSPL    8         // k2 j-split
#define JW      (OD / JSPL)      // 32 j per k2 block
#define K3SPL   4         // k3 K-split

typedef __attribute__((ext_vector_type(8))) short bf16x8;
typedef __attribute__((ext_vector_type(4))) float f32x4;

__device__ __forceinline__ short f2bf(float f) {
    __hip_bfloat16 h = __float2bfloat16(f);
    return *(short*)&h;
}

// ============ kcvt: xb = bf16(x); Mb = bf16(M); ALt = bf16(Linker^T) ============
__global__ __launch_bounds__(256) void kcvt(
    const float* __restrict__ x, const float* __restrict__ M,
    const float* __restrict__ L,
    short* __restrict__ xb, short* __restrict__ Mb, short* __restrict__ ALt)
{
    const int bid = blockIdx.x;
    const int tid = threadIdx.x;
    if (bid < 1024) {                       // x: 2048*512 = 1M elems, 4/thread
        const int i = (bid * 256 + tid) * 4;
        float4 v = *(const float4*)(x + i);
        uint lo = (ushort)f2bf(v.x) | ((uint)(ushort)f2bf(v.y) << 16);
        uint hi = (ushort)f2bf(v.z) | ((uint)(ushort)f2bf(v.w) << 16);
        *(uint2*)(xb + i) = make_uint2(lo, hi);
    } else if (bid < 1152) {                // M: 256*512 = 128K elems
        const int i = ((bid - 1024) * 256 + tid) * 4;
        float4 v = *(const float4*)(M + i);
        uint lo = (ushort)f2bf(v.x) | ((uint)(ushort)f2bf(v.y) << 16);
        uint hi = (ushort)f2bf(v.z) | ((uint)(ushort)f2bf(v.w) << 16);
        *(uint2*)(Mb + i) = make_uint2(lo, hi);
    } else {                                // Linker transpose: 32x32 tiles
        __shared__ float tl[32][36];
        const int tt = bid - 1152;          // 512 tiles: 32 s-tiles x 16 t-tiles
        const int s0 = (tt >> 4) * 32;
        const int t0 = (tt & 15) * 32;
        const int r  = tid >> 3;
        const int c4 = (tid & 7) * 4;
        float4 v = *(const float4*)(L + (size_t)(s0 + r) * TQ + t0 + c4);
        tl[r][c4 + 0] = v.x; tl[r][c4 + 1] = v.y;
        tl[r][c4 + 2] = v.z; tl[r][c4 + 3] = v.w;
        __syncthreads();
        // ALt[t0+r][s0+c4..+4] = tl[c4+q][r]
        uint lo = (ushort)f2bf(tl[c4 + 0][r]) | ((uint)(ushort)f2bf(tl[c4 + 1][r]) << 16);
        uint hi = (ushort)f2bf(tl[c4 + 2][r]) | ((uint)(ushort)f2bf(tl[c4 + 3][r]) << 16);
        *(uint2*)(ALt + (size_t)(t0 + r) * SEQL + s0 + c4) = make_uint2(lo, hi);
    }
}

// ============ shared 64x64 MFMA tile: C = A[rows][k] * B[cols][k]^T ============
// A row-major [m][k] bf16 (lda), B row-major [n][k] bf16 (ldb).
// 256 threads = 4 waves (2x2); wave -> 32x32 out = 2x2 mfma frags.
__device__ __forceinline__ void mfma_tile64(
    const short* __restrict__ A, int lda,
    const short* __restrict__ B, int ldb,
    float* __restrict__ C, int ldc,
    int r0, int c0, int k0, int nk)
{
    __shared__ short Al[64][40];   // pad to 40 bf16 (80 B rows, 16B-aligned)
    __shared__ short Bl[64][40];
    const int tid = threadIdx.x;
    const int w   = tid >> 6;
    const int wm  = w >> 1, wn = w & 1;
    const int l   = tid & 63;
    const int lr  = l & 15, lg = l >> 4;
    const int srow = tid >> 2, skg = (tid & 3) * 8;

    f32x4 acc[2][2] = {{{0.f,0.f,0.f,0.f},{0.f,0.f,0.f,0.f}},
                       {{0.f,0.f,0.f,0.f},{0.f,0.f,0.f,0.f}}};

    for (int ks = 0; ks < nk; ++ks) {
        const int kb = k0 + ks * 32;
        __syncthreads();
        *(bf16x8*)&Al[srow][skg] = *(const bf16x8*)(A + (size_t)(r0 + srow) * lda + kb + skg);
        *(bf16x8*)&Bl[srow][skg] = *(const bf16x8*)(B + (size_t)(c0 + srow) * ldb + kb + skg);
        __syncthreads();
        bf16x8 a0 = *(const bf16x8*)&Al[wm * 32 +      lr][lg * 8];
        bf16x8 a1 = *(const bf16x8*)&Al[wm * 32 + 16 + lr][lg * 8];
        bf16x8 b0 = *(const bf16x8*)&Bl[wn * 32 +      lr][lg * 8];
        bf16x8 b1 = *(const bf16x8*)&Bl[wn * 32 + 16 + lr][lg * 8];
        acc[0][0] = __builtin_amdgcn_mfma_f32_16x16x32_bf16(a0, b0, acc[0][0], 0, 0, 0);
        acc[0][1] = __builtin_amdgcn_mfma_f32_16x16x32_bf16(a0, b1, acc[0][1], 0, 0, 0);
        acc[1][0] = __builtin_amdgcn_mfma_f32_16x16x32_bf16(a1, b0, acc[1][0], 0, 0, 0);
        acc[1][1] = __builtin_amdgcn_mfma_f32_16x16x32_bf16(a1, b1, acc[1][1], 0, 0, 0);
    }
    // D: col = lane&15, row = 4*(lane>>4)+reg  [m89-verified]
#pragma unroll
    for (int sm = 0; sm < 2; ++sm)
#pragma unroll
    for (int sn = 0; sn < 2; ++sn)
#pragma unroll
    for (int q = 0; q < 4; ++q)
        C[(size_t)(r0 + wm * 32 + sm * 16 + 4 * lg + q) * ldc
          + (c0 + wn * 32 + sn * 16 + lr)] = acc[sm][sn][q];
}

// ============ K1: Zp[h] = xb * Mb^T (K-half h) ============
__global__ __launch_bounds__(256, 4) void k1_mfma(
    const short* __restrict__ xb, const short* __restrict__ Mb,
    float* __restrict__ Zp)
{
    mfma_tile64(xb, INDIM, Mb, INDIM,
                Zp + (size_t)blockIdx.z * TOT * OD, OD,
                blockIdx.x * 64, blockIdx.y * 64, blockIdx.z * 256, 8);
}

// ============ K1b: Z = Zp0+Zp1; Zn = LayerNorm(Z) ============
__global__ __launch_bounds__(256) void k1b_ln(
    const float* __restrict__ Zp,
    const float* __restrict__ gamma, const float* __restrict__ beta,
    float* __restrict__ Z, float* __restrict__ Zn)
{
    const int r0 = blockIdx.x * 8;
    const int c  = threadIdx.x;

    float acc[8];
#pragma unroll
    for (int r = 0; r < 8; ++r) {
        const size_t i = (size_t)(r0 + r) * OD + c;
        acc[r] = Zp[i] + Zp[(size_t)TOT * OD + i];
    }

    __shared__ float s1[8][4], s2[8][4];
    const int lane = c & 63;
    const int wid  = c >> 6;
#pragma unroll
    for (int r = 0; r < 8; ++r) {
        float s = acc[r], q = acc[r] * acc[r];
#pragma unroll
        for (int off = 32; off > 0; off >>= 1) {
            s += __shfl_xor(s, off, 64);
            q += __shfl_xor(q, off, 64);
        }
        if (lane == 0) { s1[r][wid] = s; s2[r][wid] = q; }
    }
    __syncthreads();
#pragma unroll
    for (int r = 0; r < 8; ++r) {
        float s  = s1[r][0] + s1[r][1] + s1[r][2] + s1[r][3];
        float q  = s2[r][0] + s2[r][1] + s2[r][2] + s2[r][3];
        float mu = s * (1.f / OD);
        float var = q * (1.f / OD) - mu * mu;
        float inv = rsqrtf(var + LN_EPS);
        float z  = acc[r];
        float zn = (z - mu) * inv * gamma[c] + beta[c];
        Z [(size_t)(r0 + r) * OD + c] = z;
        Zn[(size_t)(r0 + r) * OD + c] = zn;
    }
}

// ============ K2: T[k,i] = sum_j Zn[k,j]*P[i,j]*cos(2*pi*k/(i*256+j+2)) ============
// j-split 8 (JW=32): 4096 waves -> 4 waves/SIMD of TLP for the trans pipe.
__global__ __launch_bounds__(64) void k2_t(
    const float* __restrict__ Zn, const float* __restrict__ P,
    float* __restrict__ Tp)
{
    const int k0 = blockIdx.x * 32;
    const int i0 = blockIdx.y * 32;
    const int j0 = blockIdx.z * JW;

    __shared__ float zt[32][36];
    __shared__ float pt[32][36];

    const int tid = threadIdx.x;
#pragma unroll
    for (int it = 0; it < 4; ++it) {
        const int m = tid + it * 64;
        const int row = m >> 3;
        const int c4  = (m & 7) << 2;
        *(float4*)&zt[row][c4] = *(const float4*)(Zn + (size_t)(k0 + row) * OD + j0 + c4);
        *(float4*)&pt[row][c4] = *(const float4*)(P  + (size_t)(i0 + row) * OD + j0 + c4);
    }
    __syncthreads();

    const int tk = tid & 7;
    const int ti = tid >> 3;
    const int kb = k0 + tk * 4;
    const int ib = i0 + ti * 4;

    float kf[4];
#pragma unroll
    for (int r = 0; r < 4; ++r) kf[r] = (float)(kb + r);

    float acc[4][4];
#pragma unroll
    for (int r = 0; r < 4; ++r)
#pragma unroll
        for (int cc = 0; cc < 4; ++cc) acc[r][cc] = 0.f;

    for (int q = 0; q < JW / 4; ++q) {
        const int j = q * 4;
        float4 zv[4], pv[4];
#pragma unroll
        for (int r = 0; r < 4; ++r)  zv[r]  = *(const float4*)&zt[tk * 4 + r][j];
#pragma unroll
        for (int cc = 0; cc < 4; ++cc) pv[cc] = *(const float4*)&pt[ti * 4 + cc][j];

#pragma unroll
        for (int cc = 0; cc < 4; ++cc) {
            const float pb = (float)((ib + cc) * OD + j0 + j + 2);   // exact (< 2^24)
            const float ip0 = __builtin_amdgcn_rcpf(pb);
            const float ip1 = __builtin_amdgcn_rcpf(pb + 1.f);
            const float ip2 = __builtin_amdgcn_rcpf(pb + 2.f);
            const float ip3 = __builtin_amdgcn_rcpf(pb + 3.f);
#pragma unroll
            for (int r = 0; r < 4; ++r) {
                const float f0 = __builtin_amdgcn_fractf(kf[r] * ip0);
                const float f1 = __builtin_amdgcn_fractf(kf[r] * ip1);
                const float f2 = __builtin_amdgcn_fractf(kf[r] * ip2);
                const float f3 = __builtin_amdgcn_fractf(kf[r] * ip3);
                const float c0 = __builtin_amdgcn_cosf(f0);
                const float c1 = __builtin_amdgcn_cosf(f1);
                const float c2 = __builtin_amdgcn_cosf(f2);
                const float c3 = __builtin_amdgcn_cosf(f3);
                acc[r][cc] += zv[r].x * pv[cc].x * c0
                            + zv[r].y * pv[cc].y * c1
                            + zv[r].z * pv[cc].z * c2
                            + zv[r].w * pv[cc].w * c3;
            }
        }
    }

    float* Tpl = Tp + (size_t)blockIdx.z * (TOT * OD);
#pragma unroll
    for (int r = 0; r < 4; ++r) {
        float4 v = make_float4(acc[r][0], acc[r][1], acc[r][2], acc[r][3]);
        *(float4*)(Tpl + (size_t)(kb + r) * OD + ib) = v;
    }
}

// ============ K2b: Wt[b][o][s] = bf16(Z + sum Tp) transposed ============
__global__ __launch_bounds__(256) void k2b_w(
    const float* __restrict__ Z, const float* __restrict__ Tp,
    short* __restrict__ Wt)
{
    __shared__ float tl[64][68];
    const int kt0 = blockIdx.x * 64;    // global k = b*1024+s
    const int o0  = blockIdx.y * 64;
    const int tid = threadIdx.x;
    const int r  = tid >> 2;
    const int cq = tid & 3;

#pragma unroll
    for (int it = 0; it < 4; ++it) {
        const int col = cq * 16 + it * 4;
        const size_t idx = (size_t)(kt0 + r) * OD + o0 + col;
        float4 z = *(const float4*)(Z + idx);
#pragma unroll
        for (int p = 0; p < JSPL; ++p) {
            float4 t = *(const float4*)(Tp + (size_t)p * TOT * OD + idx);
            z.x += t.x; z.y += t.y; z.z += t.z; z.w += t.w;
        }
        *(float4*)&tl[r][col] = z;
    }
    __syncthreads();

    const int ol = tid >> 2;
    const int b  = kt0 >> 10;
    const int sb = kt0 & 1023;
    short* wrow = Wt + ((size_t)b * OD + o0 + ol) * SEQL + sb;
#pragma unroll
    for (int it = 0; it < 4; ++it) {
        const int sc = cq * 16 + it * 4;
        uint lo = (ushort)f2bf(tl[sc + 0][ol]) | ((uint)(ushort)f2bf(tl[sc + 1][ol]) << 16);
        uint hi = (ushort)f2bf(tl[sc + 2][ol]) | ((uint)(ushort)f2bf(tl[sc + 3][ol]) << 16);
        *(uint2*)(wrow + sc) = make_uint2(lo, hi);
    }
}

// ============ K3: Op[ksp][b] = ALt * Wt_b^T (s-chunk ksp) ============
__global__ __launch_bounds__(256, 4) void k3_mfma(
    const short* __restrict__ ALt, const short* __restrict__ Wt,
    float* __restrict__ Op)
{
    const int b   = blockIdx.z & 1;
    const int ksp = blockIdx.z >> 1;
    mfma_tile64(ALt, SEQL, Wt + (size_t)b * OD * SEQL, SEQL,
                Op + (size_t)ksp * (NB * TQ * OD) + (size_t)b * TQ * OD, OD,
                blockIdx.x * 64, blockIdx.y * 64, ksp * 256, 8);
}

// ============ K4: out = sum of 4 Op planes; write out_seq scalar ============
__global__ __launch_bounds__(256) void k4_comb(
    const float* __restrict__ Op, float* __restrict__ out, int out_size)
{
    const int m = blockIdx.x * 256 + threadIdx.x;   // float4 index
    const int N4 = (NB * TQ * OD) / 4;
    if (m < N4) {
        float4 a = ((const float4*)Op)[m];
#pragma unroll
        for (int p = 1; p < K3SPL; ++p) {
            float4 t = ((const float4*)(Op + (size_t)p * (NB * TQ * OD)))[m];
            a.x += t.x; a.y += t.y; a.z += t.z; a.w += t.w;
        }
        ((float4*)out)[m] = a;
    }
    if (m == 0 && out_size > NB * TQ * OD)
        out[NB * TQ * OD] = (float)TQ;   // second output: out_seq = 512
}

extern "C" void kernel_launch(void* const* d_in, const int* in_sizes, int n_in,
                              void* d_out, int out_size, void* d_ws, size_t ws_size,
                              hipStream_t stream)
{
    const float* x  = (const float*)d_in[0];
    const float* M  = (const float*)d_in[1];
    const float* P  = (const float*)d_in[2];
    const float* L  = (const float*)d_in[3];
    const float* g  = (const float*)d_in[4];
    const float* be = (const float*)d_in[5];
    float* out = (float*)d_out;

    float* ws_f = (float*)d_ws;
    float* Zp = ws_f;                               // 2 * TOT*OD
    float* Z  = Zp + 2 * (size_t)TOT * OD;          // TOT*OD
    float* Zn = Z  + (size_t)TOT * OD;              // TOT*OD
    float* Tp = Zn + (size_t)TOT * OD;              // JSPL * TOT*OD
    float* Op = Tp + (size_t)JSPL * TOT * OD;       // K3SPL * NB*TQ*OD
    short* xb  = (short*)(Op + (size_t)K3SPL * NB * TQ * OD);
    short* Mb  = xb  + (size_t)TOT * INDIM;
    short* ALt = Mb  + (size_t)OD * INDIM;
    short* Wt  = ALt + (size_t)TQ * SEQL;

    kcvt<<<1664, 256, 0, stream>>>(x, M, L, xb, Mb, ALt);
    k1_mfma<<<dim3(TOT / 64, OD / 64, 2), 256, 0, stream>>>(xb, Mb, Zp);
    k1b_ln<<<TOT / 8, 256, 0, stream>>>(Zp, g, be, Z, Zn);
    k2_t<<<dim3(TOT / 32, OD / 32, JSPL), 64, 0, stream>>>(Zn, P, Tp);
    k2b_w<<<dim3(TOT / 64, OD / 64), 256, 0, stream>>>(Z, Tp, Wt);
    k3_mfma<<<dim3(TQ / 64, OD / 64, NB * K3SPL), 256, 0, stream>>>(ALt, Wt, Op);
    k4_comb<<<(NB * TQ * OD / 4 + 255) / 256, 256, 0, stream>>>(Op, out, out_size);
}

// Round 9
// 59.139 us; speedup vs baseline: 2.4101x; 1.0375x over previous
//
#include <hip/hip_runtime.h>
#include <hip/hip_bf16.h>

#define TOT     2048      // B*SEQ rows
#define INDIM   512
#define OD      256
#define SEQL    1024
#define TQ      512       // out_seq
#define NB      2
#define LN_EPS  1e-5f

#define JSPL    16        // k2 j-split
#define JW      (OD / JSPL)      // 16 j per k2 block
#define K3SPL   8         // k3 K-split

typedef __attribute__((ext_vector_type(8))) short bf16x8;
typedef __attribute__((ext_vector_type(4))) float f32x4;

__device__ __forceinline__ short f2bf(float f) {
    __hip_bfloat16 h = __float2bfloat16(f);
    return *(short*)&h;
}
__device__ __forceinline__ uint pack2(float a, float b) {
    return (uint)(ushort)f2bf(a) | ((uint)(ushort)f2bf(b) << 16);
}

// ============ kcvt: xb = bf16(x); Mb = bf16(M); ALt = bf16(Linker^T) ============
__global__ __launch_bounds__(256) void kcvt(
    const float* __restrict__ x, const float* __restrict__ M,
    const float* __restrict__ L,
    short* __restrict__ xb, short* __restrict__ Mb, short* __restrict__ ALt)
{
    const int bid = blockIdx.x;
    const int tid = threadIdx.x;
    if (bid < 1024) {                       // x: 2048*512 = 1M elems, 4/thread
        const int i = (bid * 256 + tid) * 4;
        float4 v = *(const float4*)(x + i);
        *(uint2*)(xb + i) = make_uint2(pack2(v.x, v.y), pack2(v.z, v.w));
    } else if (bid < 1152) {                // M: 256*512 = 128K elems
        const int i = ((bid - 1024) * 256 + tid) * 4;
        float4 v = *(const float4*)(M + i);
        *(uint2*)(Mb + i) = make_uint2(pack2(v.x, v.y), pack2(v.z, v.w));
    } else {                                // Linker transpose: 32x32 tiles
        __shared__ float tl[32][36];
        const int tt = bid - 1152;          // 512 tiles: 32 s-tiles x 16 t-tiles
        const int s0 = (tt >> 4) * 32;
        const int t0 = (tt & 15) * 32;
        const int r  = tid >> 3;
        const int c4 = (tid & 7) * 4;
        float4 v = *(const float4*)(L + (size_t)(s0 + r) * TQ + t0 + c4);
        tl[r][c4 + 0] = v.x; tl[r][c4 + 1] = v.y;
        tl[r][c4 + 2] = v.z; tl[r][c4 + 3] = v.w;
        __syncthreads();
        uint lo = pack2(tl[c4 + 0][r], tl[c4 + 1][r]);
        uint hi = pack2(tl[c4 + 2][r], tl[c4 + 3][r]);
        *(uint2*)(ALt + (size_t)(t0 + r) * SEQL + s0 + c4) = make_uint2(lo, hi);
    }
}

// ============ shared 64x64 MFMA tile: C = A[rows][k] * B[cols][k]^T ============
__device__ __forceinline__ void mfma_tile64(
    const short* __restrict__ A, int lda,
    const short* __restrict__ B, int ldb,
    float* __restrict__ C, int ldc,
    int r0, int c0, int k0, int nk)
{
    __shared__ short Al[64][40];   // pad to 40 bf16 (80 B rows, 16B-aligned)
    __shared__ short Bl[64][40];
    const int tid = threadIdx.x;
    const int w   = tid >> 6;
    const int wm  = w >> 1, wn = w & 1;
    const int l   = tid & 63;
    const int lr  = l & 15, lg = l >> 4;
    const int srow = tid >> 2, skg = (tid & 3) * 8;

    f32x4 acc[2][2] = {{{0.f,0.f,0.f,0.f},{0.f,0.f,0.f,0.f}},
                       {{0.f,0.f,0.f,0.f},{0.f,0.f,0.f,0.f}}};

    for (int ks = 0; ks < nk; ++ks) {
        const int kb = k0 + ks * 32;
        __syncthreads();
        *(bf16x8*)&Al[srow][skg] = *(const bf16x8*)(A + (size_t)(r0 + srow) * lda + kb + skg);
        *(bf16x8*)&Bl[srow][skg] = *(const bf16x8*)(B + (size_t)(c0 + srow) * ldb + kb + skg);
        __syncthreads();
        bf16x8 a0 = *(const bf16x8*)&Al[wm * 32 +      lr][lg * 8];
        bf16x8 a1 = *(const bf16x8*)&Al[wm * 32 + 16 + lr][lg * 8];
        bf16x8 b0 = *(const bf16x8*)&Bl[wn * 32 +      lr][lg * 8];
        bf16x8 b1 = *(const bf16x8*)&Bl[wn * 32 + 16 + lr][lg * 8];
        acc[0][0] = __builtin_amdgcn_mfma_f32_16x16x32_bf16(a0, b0, acc[0][0], 0, 0, 0);
        acc[0][1] = __builtin_amdgcn_mfma_f32_16x16x32_bf16(a0, b1, acc[0][1], 0, 0, 0);
        acc[1][0] = __builtin_amdgcn_mfma_f32_16x16x32_bf16(a1, b0, acc[1][0], 0, 0, 0);
        acc[1][1] = __builtin_amdgcn_mfma_f32_16x16x32_bf16(a1, b1, acc[1][1], 0, 0, 0);
    }
    // D: col = lane&15, row = 4*(lane>>4)+reg  [m89-verified]
#pragma unroll
    for (int sm = 0; sm < 2; ++sm)
#pragma unroll
    for (int sn = 0; sn < 2; ++sn)
#pragma unroll
    for (int q = 0; q < 4; ++q)
        C[(size_t)(r0 + wm * 32 + sm * 16 + 4 * lg + q) * ldc
          + (c0 + wn * 32 + sn * 16 + lr)] = acc[sm][sn][q];
}

// ============ K1: Zp[h] = xb * Mb^T (K-half h) ============
__global__ __launch_bounds__(256, 4) void k1_mfma(
    const short* __restrict__ xb, const short* __restrict__ Mb,
    float* __restrict__ Zp)
{
    mfma_tile64(xb, INDIM, Mb, INDIM,
                Zp + (size_t)blockIdx.z * TOT * OD, OD,
                blockIdx.x * 64, blockIdx.y * 64, blockIdx.z * 256, 8);
}

// ============ K1b: Z = Zp0+Zp1; Zn = LayerNorm(Z) ============
__global__ __launch_bounds__(256) void k1b_ln(
    const float* __restrict__ Zp,
    const float* __restrict__ gamma, const float* __restrict__ beta,
    float* __restrict__ Z, float* __restrict__ Zn)
{
    const int r0 = blockIdx.x * 8;
    const int c  = threadIdx.x;

    float acc[8];
#pragma unroll
    for (int r = 0; r < 8; ++r) {
        const size_t i = (size_t)(r0 + r) * OD + c;
        acc[r] = Zp[i] + Zp[(size_t)TOT * OD + i];
    }

    __shared__ float s1[8][4], s2[8][4];
    const int lane = c & 63;
    const int wid  = c >> 6;
#pragma unroll
    for (int r = 0; r < 8; ++r) {
        float s = acc[r], q = acc[r] * acc[r];
#pragma unroll
        for (int off = 32; off > 0; off >>= 1) {
            s += __shfl_xor(s, off, 64);
            q += __shfl_xor(q, off, 64);
        }
        if (lane == 0) { s1[r][wid] = s; s2[r][wid] = q; }
    }
    __syncthreads();
#pragma unroll
    for (int r = 0; r < 8; ++r) {
        float s  = s1[r][0] + s1[r][1] + s1[r][2] + s1[r][3];
        float q  = s2[r][0] + s2[r][1] + s2[r][2] + s2[r][3];
        float mu = s * (1.f / OD);
        float var = q * (1.f / OD) - mu * mu;
        float inv = rsqrtf(var + LN_EPS);
        float z  = acc[r];
        float zn = (z - mu) * inv * gamma[c] + beta[c];
        Z [(size_t)(r0 + r) * OD + c] = z;
        Zn[(size_t)(r0 + r) * OD + c] = zn;
    }
}

// ============ K2: T[k,i] = sum_j Zn[k,j]*P[i,j]*cos(2*pi*k/(i*256+j+2)) ============
// j-split 16 (JW=16): 8192 blocks -> 8 waves/SIMD TLP. Tp stored bf16.
__global__ __launch_bounds__(64) void k2_t(
    const float* __restrict__ Zn, const float* __restrict__ P,
    short* __restrict__ Tp)
{
    const int k0 = blockIdx.x * 32;
    const int i0 = blockIdx.y * 32;
    const int j0 = blockIdx.z * JW;

    __shared__ float zt[32][20];   // stride 20: 8-row b128 pattern conflict-free
    __shared__ float pt[32][20];

    const int tid = threadIdx.x;
#pragma unroll
    for (int it = 0; it < 2; ++it) {
        const int m = tid + it * 64;      // 0..127
        const int row = m >> 2;           // 0..31
        const int c4  = (m & 3) << 2;     // 0,4,8,12
        *(float4*)&zt[row][c4] = *(const float4*)(Zn + (size_t)(k0 + row) * OD + j0 + c4);
        *(float4*)&pt[row][c4] = *(const float4*)(P  + (size_t)(i0 + row) * OD + j0 + c4);
    }
    __syncthreads();

    const int tk = tid & 7;
    const int ti = tid >> 3;
    const int kb = k0 + tk * 4;
    const int ib = i0 + ti * 4;

    float kf[4];
#pragma unroll
    for (int r = 0; r < 4; ++r) kf[r] = (float)(kb + r);

    float acc[4][4];
#pragma unroll
    for (int r = 0; r < 4; ++r)
#pragma unroll
        for (int cc = 0; cc < 4; ++cc) acc[r][cc] = 0.f;

#pragma unroll
    for (int q = 0; q < JW / 4; ++q) {
        const int j = q * 4;
        float4 zv[4], pv[4];
#pragma unroll
        for (int r = 0; r < 4; ++r)  zv[r]  = *(const float4*)&zt[tk * 4 + r][j];
#pragma unroll
        for (int cc = 0; cc < 4; ++cc) pv[cc] = *(const float4*)&pt[ti * 4 + cc][j];

#pragma unroll
        for (int cc = 0; cc < 4; ++cc) {
            const float pb = (float)((ib + cc) * OD + j0 + j + 2);   // exact (< 2^24)
            const float ip0 = __builtin_amdgcn_rcpf(pb);
            const float ip1 = __builtin_amdgcn_rcpf(pb + 1.f);
            const float ip2 = __builtin_amdgcn_rcpf(pb + 2.f);
            const float ip3 = __builtin_amdgcn_rcpf(pb + 3.f);
#pragma unroll
            for (int r = 0; r < 4; ++r) {
                const float f0 = __builtin_amdgcn_fractf(kf[r] * ip0);
                const float f1 = __builtin_amdgcn_fractf(kf[r] * ip1);
                const float f2 = __builtin_amdgcn_fractf(kf[r] * ip2);
                const float f3 = __builtin_amdgcn_fractf(kf[r] * ip3);
                const float c0 = __builtin_amdgcn_cosf(f0);
                const float c1 = __builtin_amdgcn_cosf(f1);
                const float c2 = __builtin_amdgcn_cosf(f2);
                const float c3 = __builtin_amdgcn_cosf(f3);
                acc[r][cc] += zv[r].x * pv[cc].x * c0
                            + zv[r].y * pv[cc].y * c1
                            + zv[r].z * pv[cc].z * c2
                            + zv[r].w * pv[cc].w * c3;
            }
        }
    }

    short* Tpl = Tp + (size_t)blockIdx.z * (TOT * OD);
#pragma unroll
    for (int r = 0; r < 4; ++r) {
        uint2 v = make_uint2(pack2(acc[r][0], acc[r][1]), pack2(acc[r][2], acc[r][3]));
        *(uint2*)(Tpl + (size_t)(kb + r) * OD + ib) = v;
    }
}

// ============ K2b: Wt[b][o][s] = bf16(Z + sum Tp) transposed ============
// 32x32 tiles -> 512 blocks (2 waves/SIMD).
__global__ __launch_bounds__(256) void k2b_w(
    const float* __restrict__ Z, const short* __restrict__ Tp,
    short* __restrict__ Wt)
{
    __shared__ float tl[32][36];
    const int kt0 = blockIdx.x * 32;    // global k = b*1024+s
    const int o0  = blockIdx.y * 32;
    const int tid = threadIdx.x;
    const int r   = tid >> 3;           // 0..31 (kt row)
    const int c4  = (tid & 7) * 4;      // 0..28 (o col)

    const size_t idx = (size_t)(kt0 + r) * OD + o0 + c4;
    float4 z = *(const float4*)(Z + idx);
#pragma unroll
    for (int p = 0; p < JSPL; ++p) {
        uint2 t = *(const uint2*)(Tp + (size_t)p * (TOT * OD) + idx);
        z.x += __uint_as_float(t.x << 16);
        z.y += __uint_as_float(t.x & 0xFFFF0000u);
        z.z += __uint_as_float(t.y << 16);
        z.w += __uint_as_float(t.y & 0xFFFF0000u);
    }
    *(float4*)&tl[r][c4] = z;
    __syncthreads();

    const int ol = tid >> 3;            // 0..31 (o row out)
    const int sc = (tid & 7) * 4;       // 0..28 (s col out)
    const int b  = kt0 >> 10;
    const int sb = kt0 & 1023;
    uint lo = pack2(tl[sc + 0][ol], tl[sc + 1][ol]);
    uint hi = pack2(tl[sc + 2][ol], tl[sc + 3][ol]);
    *(uint2*)(Wt + ((size_t)b * OD + o0 + ol) * SEQL + sb + sc) = make_uint2(lo, hi);
}

// ============ K3: Op[ksp][b] = ALt * Wt_b^T (s-chunk ksp) ============
__global__ __launch_bounds__(256, 4) void k3_mfma(
    const short* __restrict__ ALt, const short* __restrict__ Wt,
    float* __restrict__ Op)
{
    const int b   = blockIdx.z & 1;
    const int ksp = blockIdx.z >> 1;
    mfma_tile64(ALt, SEQL, Wt + (size_t)b * OD * SEQL, SEQL,
                Op + (size_t)ksp * (NB * TQ * OD) + (size_t)b * TQ * OD, OD,
                blockIdx.x * 64, blockIdx.y * 64, ksp * (SEQL / K3SPL), (SEQL / K3SPL) / 32);
}

// ============ K4: out = sum of 8 Op planes; write out_seq scalar ============
__global__ __launch_bounds__(256) void k4_comb(
    const float* __restrict__ Op, float* __restrict__ out, int out_size)
{
    const int m = blockIdx.x * 256 + threadIdx.x;   // float4 index
    const int N4 = (NB * TQ * OD) / 4;
    if (m < N4) {
        float4 a = ((const float4*)Op)[m];
#pragma unroll
        for (int p = 1; p < K3SPL; ++p) {
            float4 t = ((const float4*)(Op + (size_t)p * (NB * TQ * OD)))[m];
            a.x += t.x; a.y += t.y; a.z += t.z; a.w += t.w;
        }
        ((float4*)out)[m] = a;
    }
    if (m == 0 && out_size > NB * TQ * OD)
        out[NB * TQ * OD] = (float)TQ;   // second output: out_seq = 512
}

extern "C" void kernel_launch(void* const* d_in, const int* in_sizes, int n_in,
                              void* d_out, int out_size, void* d_ws, size_t ws_size,
                              hipStream_t stream)
{
    const float* x  = (const float*)d_in[0];
    const float* M  = (const float*)d_in[1];
    const float* P  = (const float*)d_in[2];
    const float* L  = (const float*)d_in[3];
    const float* g  = (const float*)d_in[4];
    const float* be = (const float*)d_in[5];
    float* out = (float*)d_out;

    float* ws_f = (float*)d_ws;
    float* Zp = ws_f;                               // 2 * TOT*OD f32
    float* Z  = Zp + 2 * (size_t)TOT * OD;          // TOT*OD f32
    float* Zn = Z  + (size_t)TOT * OD;              // TOT*OD f32
    float* Op = Zn + (size_t)TOT * OD;              // K3SPL * NB*TQ*OD f32
    short* xb  = (short*)(Op + (size_t)K3SPL * NB * TQ * OD);
    short* Mb  = xb  + (size_t)TOT * INDIM;
    short* ALt = Mb  + (size_t)OD * INDIM;
    short* Wt  = ALt + (size_t)TQ * SEQL;
    short* Tp  = Wt  + (size_t)NB * OD * SEQL;      // JSPL * TOT*OD bf16

    kcvt<<<1664, 256, 0, stream>>>(x, M, L, xb, Mb, ALt);
    k1_mfma<<<dim3(TOT / 64, OD / 64, 2), 256, 0, stream>>>(xb, Mb, Zp);
    k1b_ln<<<TOT / 8, 256, 0, stream>>>(Zp, g, be, Z, Zn);
    k2_t<<<dim3(TOT / 32, OD / 32, JSPL), 64, 0, stream>>>(Zn, P, Tp);
    k2b_w<<<dim3(TOT / 32, OD / 32), 256, 0, stream>>>(Z, Tp, Wt);
    k3_mfma<<<dim3(TQ / 64, OD / 64, NB * K3SPL), 256, 0, stream>>>(ALt, Wt, Op);
    k4_comb<<<(NB * TQ * OD / 4 + 255) / 256, 256, 0, stream>>>(Op, out, out_size);
}

// Round 10
// 53.949 us; speedup vs baseline: 2.6419x; 1.0962x over previous
//
#include <hip/hip_runtime.h>
#include <hip/hip_bf16.h>

#define TOT     2048      // B*SEQ rows
#define INDIM   512
#define OD      256
#define SEQL    1024
#define TQ      512       // out_seq
#define NB      2
#define LN_EPS  1e-5f

#define JSPL    16        // k2 j-split (planes)
#define JW      (OD / JSPL)      // 16 j per k2 block
#define K3SPL   8         // k3 K-split

typedef __attribute__((ext_vector_type(8))) short bf16x8;
typedef __attribute__((ext_vector_type(4))) float f32x4;
typedef __attribute__((ext_vector_type(2))) float f32x2;

__device__ __forceinline__ short f2bf(float f) {
    __hip_bfloat16 h = __float2bfloat16(f);
    return *(short*)&h;
}
__device__ __forceinline__ uint pack2(float a, float b) {
    return (uint)(ushort)f2bf(a) | ((uint)(ushort)f2bf(b) << 16);
}

// ============ kcvt: xb = bf16(x); Mb = bf16(M); ALt = bf16(Linker^T) ============
__global__ __launch_bounds__(256) void kcvt(
    const float* __restrict__ x, const float* __restrict__ M,
    const float* __restrict__ L,
    short* __restrict__ xb, short* __restrict__ Mb, short* __restrict__ ALt)
{
    const int bid = blockIdx.x;
    const int tid = threadIdx.x;
    if (bid < 1024) {                       // x: 2048*512 = 1M elems, 4/thread
        const int i = (bid * 256 + tid) * 4;
        float4 v = *(const float4*)(x + i);
        *(uint2*)(xb + i) = make_uint2(pack2(v.x, v.y), pack2(v.z, v.w));
    } else if (bid < 1152) {                // M: 256*512 = 128K elems
        const int i = ((bid - 1024) * 256 + tid) * 4;
        float4 v = *(const float4*)(M + i);
        *(uint2*)(Mb + i) = make_uint2(pack2(v.x, v.y), pack2(v.z, v.w));
    } else {                                // Linker transpose: 32x32 tiles
        __shared__ float tl[32][36];
        const int tt = bid - 1152;          // 512 tiles: 32 s-tiles x 16 t-tiles
        const int s0 = (tt >> 4) * 32;
        const int t0 = (tt & 15) * 32;
        const int r  = tid >> 3;
        const int c4 = (tid & 7) * 4;
        float4 v = *(const float4*)(L + (size_t)(s0 + r) * TQ + t0 + c4);
        tl[r][c4 + 0] = v.x; tl[r][c4 + 1] = v.y;
        tl[r][c4 + 2] = v.z; tl[r][c4 + 3] = v.w;
        __syncthreads();
        uint lo = pack2(tl[c4 + 0][r], tl[c4 + 1][r]);
        uint hi = pack2(tl[c4 + 2][r], tl[c4 + 3][r]);
        *(uint2*)(ALt + (size_t)(t0 + r) * SEQL + s0 + c4) = make_uint2(lo, hi);
    }
}

// ============ shared 64x64 MFMA tile: C = A[rows][k] * B[cols][k]^T ============
__device__ __forceinline__ void mfma_tile64(
    const short* __restrict__ A, int lda,
    const short* __restrict__ B, int ldb,
    float* __restrict__ C, int ldc,
    int r0, int c0, int k0, int nk)
{
    __shared__ short Al[64][40];   // pad to 40 bf16 (80 B rows, 16B-aligned)
    __shared__ short Bl[64][40];
    const int tid = threadIdx.x;
    const int w   = tid >> 6;
    const int wm  = w >> 1, wn = w & 1;
    const int l   = tid & 63;
    const int lr  = l & 15, lg = l >> 4;
    const int srow = tid >> 2, skg = (tid & 3) * 8;

    f32x4 acc[2][2] = {{{0.f,0.f,0.f,0.f},{0.f,0.f,0.f,0.f}},
                       {{0.f,0.f,0.f,0.f},{0.f,0.f,0.f,0.f}}};

    for (int ks = 0; ks < nk; ++ks) {
        const int kb = k0 + ks * 32;
        __syncthreads();
        *(bf16x8*)&Al[srow][skg] = *(const bf16x8*)(A + (size_t)(r0 + srow) * lda + kb + skg);
        *(bf16x8*)&Bl[srow][skg] = *(const bf16x8*)(B + (size_t)(c0 + srow) * ldb + kb + skg);
        __syncthreads();
        bf16x8 a0 = *(const bf16x8*)&Al[wm * 32 +      lr][lg * 8];
        bf16x8 a1 = *(const bf16x8*)&Al[wm * 32 + 16 + lr][lg * 8];
        bf16x8 b0 = *(const bf16x8*)&Bl[wn * 32 +      lr][lg * 8];
        bf16x8 b1 = *(const bf16x8*)&Bl[wn * 32 + 16 + lr][lg * 8];
        acc[0][0] = __builtin_amdgcn_mfma_f32_16x16x32_bf16(a0, b0, acc[0][0], 0, 0, 0);
        acc[0][1] = __builtin_amdgcn_mfma_f32_16x16x32_bf16(a0, b1, acc[0][1], 0, 0, 0);
        acc[1][0] = __builtin_amdgcn_mfma_f32_16x16x32_bf16(a1, b0, acc[1][0], 0, 0, 0);
        acc[1][1] = __builtin_amdgcn_mfma_f32_16x16x32_bf16(a1, b1, acc[1][1], 0, 0, 0);
    }
    // D: col = lane&15, row = 4*(lane>>4)+reg  [m89-verified]
#pragma unroll
    for (int sm = 0; sm < 2; ++sm)
#pragma unroll
    for (int sn = 0; sn < 2; ++sn)
#pragma unroll
    for (int q = 0; q < 4; ++q)
        C[(size_t)(r0 + wm * 32 + sm * 16 + 4 * lg + q) * ldc
          + (c0 + wn * 32 + sn * 16 + lr)] = acc[sm][sn][q];
}

// ============ K1: Zp[h] = xb * Mb^T (K-half h) ============
__global__ __launch_bounds__(256, 4) void k1_mfma(
    const short* __restrict__ xb, const short* __restrict__ Mb,
    float* __restrict__ Zp)
{
    mfma_tile64(xb, INDIM, Mb, INDIM,
                Zp + (size_t)blockIdx.z * TOT * OD, OD,
                blockIdx.x * 64, blockIdx.y * 64, blockIdx.z * 256, 8);
}

// ============ K1b: Z = Zp0+Zp1; Zn = LayerNorm(Z) ============
__global__ __launch_bounds__(256) void k1b_ln(
    const float* __restrict__ Zp,
    const float* __restrict__ gamma, const float* __restrict__ beta,
    float* __restrict__ Z, float* __restrict__ Zn)
{
    const int r0 = blockIdx.x * 8;
    const int c  = threadIdx.x;

    float acc[8];
#pragma unroll
    for (int r = 0; r < 8; ++r) {
        const size_t i = (size_t)(r0 + r) * OD + c;
        acc[r] = Zp[i] + Zp[(size_t)TOT * OD + i];
    }

    __shared__ float s1[8][4], s2[8][4];
    const int lane = c & 63;
    const int wid  = c >> 6;
#pragma unroll
    for (int r = 0; r < 8; ++r) {
        float s = acc[r], q = acc[r] * acc[r];
#pragma unroll
        for (int off = 32; off > 0; off >>= 1) {
            s += __shfl_xor(s, off, 64);
            q += __shfl_xor(q, off, 64);
        }
        if (lane == 0) { s1[r][wid] = s; s2[r][wid] = q; }
    }
    __syncthreads();
#pragma unroll
    for (int r = 0; r < 8; ++r) {
        float s  = s1[r][0] + s1[r][1] + s1[r][2] + s1[r][3];
        float q  = s2[r][0] + s2[r][1] + s2[r][2] + s2[r][3];
        float mu = s * (1.f / OD);
        float var = q * (1.f / OD) - mu * mu;
        float inv = rsqrtf(var + LN_EPS);
        float z  = acc[r];
        float zn = (z - mu) * inv * gamma[c] + beta[c];
        Z [(size_t)(r0 + r) * OD + c] = z;
        Zn[(size_t)(r0 + r) * OD + c] = zn;
    }
}

// ============ K2: T[k,i] = sum_j Zn[k,j]*P[i,j]*cos(2*pi*k/(i*256+j+2)) ============
// Rotation recurrence over k: per (j,lane) 4 trans + 1 rcp set up cos/sin at
// (k0, k0+1) and the 2*delta rotator; 16 k-pairs advance via packed-f32
// (f32x2 -> v_pk_fma_f32) rotations. 31/32 of cos/sin eliminated.
// Block: 64k x 32i x 16j; lane (kg, li) owns 32k x 1i.
__global__ __launch_bounds__(64) void k2_t(
    const float* __restrict__ Zn, const float* __restrict__ P,
    short* __restrict__ Tp)
{
    const int k0 = blockIdx.x * 64;
    const int i0 = blockIdx.y * 32;
    const int j0 = blockIdx.z * JW;

    __shared__ float znT[JW][68];   // [j_local][k_local], 272B rows (16B-aligned)
    __shared__ float pt[32][20];    // [i_local][j_local], 80B rows

    const int tid = threadIdx.x;
    {
        const float* zr = Zn + (size_t)(k0 + tid) * OD + j0;
        float4 v0 = *(const float4*)(zr);
        float4 v1 = *(const float4*)(zr + 4);
        float4 v2 = *(const float4*)(zr + 8);
        float4 v3 = *(const float4*)(zr + 12);
        znT[ 0][tid] = v0.x; znT[ 1][tid] = v0.y; znT[ 2][tid] = v0.z; znT[ 3][tid] = v0.w;
        znT[ 4][tid] = v1.x; znT[ 5][tid] = v1.y; znT[ 6][tid] = v1.z; znT[ 7][tid] = v1.w;
        znT[ 8][tid] = v2.x; znT[ 9][tid] = v2.y; znT[10][tid] = v2.z; znT[11][tid] = v2.w;
        znT[12][tid] = v3.x; znT[13][tid] = v3.y; znT[14][tid] = v3.z; znT[15][tid] = v3.w;
        if (tid < 32) {
            const float* pr = P + (size_t)(i0 + tid) * OD + j0;
            *(float4*)&pt[tid][ 0] = *(const float4*)(pr);
            *(float4*)&pt[tid][ 4] = *(const float4*)(pr + 4);
            *(float4*)&pt[tid][ 8] = *(const float4*)(pr + 8);
            *(float4*)&pt[tid][12] = *(const float4*)(pr + 12);
        }
    }
    __syncthreads();

    const int kg = tid & 1;        // k half: 0 -> k0.., 1 -> k0+32..
    const int li = tid >> 1;       // i local 0..31
    const float kbase = (float)(k0 + kg * 32);
    const float pb0   = (float)((i0 + li) * OD + j0 + 2);   // exact (< 2^24)

    f32x2 acc[16];
#pragma unroll
    for (int m = 0; m < 16; ++m) acc[m] = (f32x2){0.f, 0.f};

    const float* zrow = &znT[0][kg * 32];

    for (int j = 0; j < JW; ++j) {
        const float p  = pb0 + (float)j;
        const float ip = __builtin_amdgcn_rcpf(p);            // delta in revolutions
        const float a0 = __builtin_amdgcn_fractf(kbase * ip);
        const float c0 = __builtin_amdgcn_cosf(a0);
        const float s0 = __builtin_amdgcn_sinf(a0);
        const float cd = __builtin_amdgcn_cosf(ip);           // ip <= 0.5: no fract
        const float sd = __builtin_amdgcn_sinf(ip);
        const float c1 = c0 * cd - s0 * sd;                   // angle k+1
        const float s1 = s0 * cd + c0 * sd;
        const float c2d = 1.f - 2.f * sd * sd;                // rotator 2*delta
        const float s2d = 2.f * sd * cd;

        f32x2 C = {c0, c1}, S = {s0, s1};
        const f32x2 C2 = {c2d, c2d}, S2 = {s2d, s2d};
        const float pm = pt[li][j];
        const f32x2 PM = {pm, pm};
        const float* zc = zrow + (size_t)j * 68;

#pragma unroll
        for (int m8 = 0; m8 < 8; ++m8) {
            float4 z4 = *(const float4*)(zc + 4 * m8);
            f32x2 za = {z4.x, z4.y};
            f32x2 zb = {z4.z, z4.w};
            f32x2 t = za * PM;
            acc[2 * m8] = t * C + acc[2 * m8];
            f32x2 Cn = C * C2 - S * S2;
            f32x2 Sn = S * C2 + C * S2;
            C = Cn; S = Sn;
            t = zb * PM;
            acc[2 * m8 + 1] = t * C + acc[2 * m8 + 1];
            Cn = C * C2 - S * S2;
            Sn = S * C2 + C * S2;
            C = Cn; S = Sn;
        }
    }

    short* Tpl = Tp + (size_t)blockIdx.z * (TOT * OD);
    const int ib = i0 + li;
    const int kb = k0 + kg * 32;
#pragma unroll
    for (int m = 0; m < 16; ++m) {
        Tpl[(size_t)(kb + 2 * m    ) * OD + ib] = f2bf(acc[m].x);
        Tpl[(size_t)(kb + 2 * m + 1) * OD + ib] = f2bf(acc[m].y);
    }
}

// ============ K2b: Wt[b][o][s] = bf16(Z + sum Tp) transposed ============
// 32x32 tiles -> 512 blocks (2 waves/SIMD).
__global__ __launch_bounds__(256) void k2b_w(
    const float* __restrict__ Z, const short* __restrict__ Tp,
    short* __restrict__ Wt)
{
    __shared__ float tl[32][36];
    const int kt0 = blockIdx.x * 32;    // global k = b*1024+s
    const int o0  = blockIdx.y * 32;
    const int tid = threadIdx.x;
    const int r   = tid >> 3;           // 0..31 (kt row)
    const int c4  = (tid & 7) * 4;      // 0..28 (o col)

    const size_t idx = (size_t)(kt0 + r) * OD + o0 + c4;
    float4 z = *(const float4*)(Z + idx);
#pragma unroll
    for (int p = 0; p < JSPL; ++p) {
        uint2 t = *(const uint2*)(Tp + (size_t)p * (TOT * OD) + idx);
        z.x += __uint_as_float(t.x << 16);
        z.y += __uint_as_float(t.x & 0xFFFF0000u);
        z.z += __uint_as_float(t.y << 16);
        z.w += __uint_as_float(t.y & 0xFFFF0000u);
    }
    *(float4*)&tl[r][c4] = z;
    __syncthreads();

    const int ol = tid >> 3;            // 0..31 (o row out)
    const int sc = (tid & 7) * 4;       // 0..28 (s col out)
    const int b  = kt0 >> 10;
    const int sb = kt0 & 1023;
    uint lo = pack2(tl[sc + 0][ol], tl[sc + 1][ol]);
    uint hi = pack2(tl[sc + 2][ol], tl[sc + 3][ol]);
    *(uint2*)(Wt + ((size_t)b * OD + o0 + ol) * SEQL + sb + sc) = make_uint2(lo, hi);
}

// ============ K3: Op[ksp][b] = ALt * Wt_b^T (s-chunk ksp) ============
__global__ __launch_bounds__(256, 4) void k3_mfma(
    const short* __restrict__ ALt, const short* __restrict__ Wt,
    float* __restrict__ Op)
{
    const int b   = blockIdx.z & 1;
    const int ksp = blockIdx.z >> 1;
    mfma_tile64(ALt, SEQL, Wt + (size_t)b * OD * SEQL, SEQL,
                Op + (size_t)ksp * (NB * TQ * OD) + (size_t)b * TQ * OD, OD,
                blockIdx.x * 64, blockIdx.y * 64, ksp * (SEQL / K3SPL), (SEQL / K3SPL) / 32);
}

// ============ K4: out = sum of 8 Op planes; write out_seq scalar ============
__global__ __launch_bounds__(256) void k4_comb(
    const float* __restrict__ Op, float* __restrict__ out, int out_size)
{
    const int m = blockIdx.x * 256 + threadIdx.x;   // float4 index
    const int N4 = (NB * TQ * OD) / 4;
    if (m < N4) {
        float4 a = ((const float4*)Op)[m];
#pragma unroll
        for (int p = 1; p < K3SPL; ++p) {
            float4 t = ((const float4*)(Op + (size_t)p * (NB * TQ * OD)))[m];
            a.x += t.x; a.y += t.y; a.z += t.z; a.w += t.w;
        }
        ((float4*)out)[m] = a;
    }
    if (m == 0 && out_size > NB * TQ * OD)
        out[NB * TQ * OD] = (float)TQ;   // second output: out_seq = 512
}

extern "C" void kernel_launch(void* const* d_in, const int* in_sizes, int n_in,
                              void* d_out, int out_size, void* d_ws, size_t ws_size,
                              hipStream_t stream)
{
    const float* x  = (const float*)d_in[0];
    const float* M  = (const float*)d_in[1];
    const float* P  = (const float*)d_in[2];
    const float* L  = (const float*)d_in[3];
    const float* g  = (const float*)d_in[4];
    const float* be = (const float*)d_in[5];
    float* out = (float*)d_out;

    float* ws_f = (float*)d_ws;
    float* Zp = ws_f;                               // 2 * TOT*OD f32
    float* Z  = Zp + 2 * (size_t)TOT * OD;          // TOT*OD f32
    float* Zn = Z  + (size_t)TOT * OD;              // TOT*OD f32
    float* Op = Zn + (size_t)TOT * OD;              // K3SPL * NB*TQ*OD f32
    short* xb  = (short*)(Op + (size_t)K3SPL * NB * TQ * OD);
    short* Mb  = xb  + (size_t)TOT * INDIM;
    short* ALt = Mb  + (size_t)OD * INDIM;
    short* Wt  = ALt + (size_t)TQ * SEQL;
    short* Tp  = Wt  + (size_t)NB * OD * SEQL;      // JSPL * TOT*OD bf16

    kcvt<<<1664, 256, 0, stream>>>(x, M, L, xb, Mb, ALt);
    k1_mfma<<<dim3(TOT / 64, OD / 64, 2), 256, 0, stream>>>(xb, Mb, Zp);
    k1b_ln<<<TOT / 8, 256, 0, stream>>>(Zp, g, be, Z, Zn);
    k2_t<<<dim3(TOT / 64, OD / 32, JSPL), 64, 0, stream>>>(Zn, P, Tp);
    k2b_w<<<dim3(TOT / 32, OD / 32), 256, 0, stream>>>(Z, Tp, Wt);
    k3_mfma<<<dim3(TQ / 64, OD / 64, NB * K3SPL), 256, 0, stream>>>(ALt, Wt, Op);
    k4_comb<<<(NB * TQ * OD / 4 + 255) / 256, 256, 0, stream>>>(Op, out, out_size);
}

// Round 11
// 47.394 us; speedup vs baseline: 3.0073x; 1.1383x over previous
//
#include <hip/hip_runtime.h>
#include <hip/hip_bf16.h>

#define TOT     2048      // B*SEQ rows
#define INDIM   512
#define OD      256
#define SEQL    1024
#define TQ      512       // out_seq
#define NB      2
#define LN_EPS  1e-5f

#define JSPL    16        // k2 j-split (planes)
#define JW      (OD / JSPL)      // 16 j per k2 block
#define K3SPL   8         // k3 K-split

typedef __attribute__((ext_vector_type(8))) short bf16x8;
typedef __attribute__((ext_vector_type(4))) float f32x4;
typedef __attribute__((ext_vector_type(2))) float f32x2;

__device__ __forceinline__ short f2bf(float f) {
    __hip_bfloat16 h = __float2bfloat16(f);
    return *(short*)&h;
}
__device__ __forceinline__ uint pack2(float a, float b) {
    return (uint)(ushort)f2bf(a) | ((uint)(ushort)f2bf(b) << 16);
}

// ============ kcvt: xb = bf16(x); Mb = bf16(M); ALt = bf16(Linker^T) ============
__global__ __launch_bounds__(256) void kcvt(
    const float* __restrict__ x, const float* __restrict__ M,
    const float* __restrict__ L,
    short* __restrict__ xb, short* __restrict__ Mb, short* __restrict__ ALt)
{
    const int bid = blockIdx.x;
    const int tid = threadIdx.x;
    if (bid < 1024) {                       // x: 2048*512 = 1M elems, 4/thread
        const int i = (bid * 256 + tid) * 4;
        float4 v = *(const float4*)(x + i);
        *(uint2*)(xb + i) = make_uint2(pack2(v.x, v.y), pack2(v.z, v.w));
    } else if (bid < 1152) {                // M: 256*512 = 128K elems
        const int i = ((bid - 1024) * 256 + tid) * 4;
        float4 v = *(const float4*)(M + i);
        *(uint2*)(Mb + i) = make_uint2(pack2(v.x, v.y), pack2(v.z, v.w));
    } else {                                // Linker transpose: 32x32 tiles
        __shared__ float tl[32][36];
        const int tt = bid - 1152;          // 512 tiles: 32 s-tiles x 16 t-tiles
        const int s0 = (tt >> 4) * 32;
        const int t0 = (tt & 15) * 32;
        const int r  = tid >> 3;
        const int c4 = (tid & 7) * 4;
        float4 v = *(const float4*)(L + (size_t)(s0 + r) * TQ + t0 + c4);
        tl[r][c4 + 0] = v.x; tl[r][c4 + 1] = v.y;
        tl[r][c4 + 2] = v.z; tl[r][c4 + 3] = v.w;
        __syncthreads();
        uint lo = pack2(tl[c4 + 0][r], tl[c4 + 1][r]);
        uint hi = pack2(tl[c4 + 2][r], tl[c4 + 3][r]);
        *(uint2*)(ALt + (size_t)(t0 + r) * SEQL + s0 + c4) = make_uint2(lo, hi);
    }
}

// ============ shared 64x64 MFMA tile: C = A[rows][k] * B[cols][k]^T ============
__device__ __forceinline__ void mfma_tile64(
    const short* __restrict__ A, int lda,
    const short* __restrict__ B, int ldb,
    float* __restrict__ C, int ldc,
    int r0, int c0, int k0, int nk)
{
    __shared__ short Al[64][40];   // pad to 40 bf16 (80 B rows, 16B-aligned)
    __shared__ short Bl[64][40];
    const int tid = threadIdx.x;
    const int w   = tid >> 6;
    const int wm  = w >> 1, wn = w & 1;
    const int l   = tid & 63;
    const int lr  = l & 15, lg = l >> 4;
    const int srow = tid >> 2, skg = (tid & 3) * 8;

    f32x4 acc[2][2] = {{{0.f,0.f,0.f,0.f},{0.f,0.f,0.f,0.f}},
                       {{0.f,0.f,0.f,0.f},{0.f,0.f,0.f,0.f}}};

    for (int ks = 0; ks < nk; ++ks) {
        const int kb = k0 + ks * 32;
        __syncthreads();
        *(bf16x8*)&Al[srow][skg] = *(const bf16x8*)(A + (size_t)(r0 + srow) * lda + kb + skg);
        *(bf16x8*)&Bl[srow][skg] = *(const bf16x8*)(B + (size_t)(c0 + srow) * ldb + kb + skg);
        __syncthreads();
        bf16x8 a0 = *(const bf16x8*)&Al[wm * 32 +      lr][lg * 8];
        bf16x8 a1 = *(const bf16x8*)&Al[wm * 32 + 16 + lr][lg * 8];
        bf16x8 b0 = *(const bf16x8*)&Bl[wn * 32 +      lr][lg * 8];
        bf16x8 b1 = *(const bf16x8*)&Bl[wn * 32 + 16 + lr][lg * 8];
        acc[0][0] = __builtin_amdgcn_mfma_f32_16x16x32_bf16(a0, b0, acc[0][0], 0, 0, 0);
        acc[0][1] = __builtin_amdgcn_mfma_f32_16x16x32_bf16(a0, b1, acc[0][1], 0, 0, 0);
        acc[1][0] = __builtin_amdgcn_mfma_f32_16x16x32_bf16(a1, b0, acc[1][0], 0, 0, 0);
        acc[1][1] = __builtin_amdgcn_mfma_f32_16x16x32_bf16(a1, b1, acc[1][1], 0, 0, 0);
    }
    // D: col = lane&15, row = 4*(lane>>4)+reg  [m89-verified]
#pragma unroll
    for (int sm = 0; sm < 2; ++sm)
#pragma unroll
    for (int sn = 0; sn < 2; ++sn)
#pragma unroll
    for (int q = 0; q < 4; ++q)
        C[(size_t)(r0 + wm * 32 + sm * 16 + 4 * lg + q) * ldc
          + (c0 + wn * 32 + sn * 16 + lr)] = acc[sm][sn][q];
}

// ============ K1: Zp[h] = xb * Mb^T (K-half h) ============
__global__ __launch_bounds__(256, 4) void k1_mfma(
    const short* __restrict__ xb, const short* __restrict__ Mb,
    float* __restrict__ Zp)
{
    mfma_tile64(xb, INDIM, Mb, INDIM,
                Zp + (size_t)blockIdx.z * TOT * OD, OD,
                blockIdx.x * 64, blockIdx.y * 64, blockIdx.z * 256, 8);
}

// ============ K1b: Z = Zp0+Zp1; Zn = LayerNorm(Z) ============
__global__ __launch_bounds__(256) void k1b_ln(
    const float* __restrict__ Zp,
    const float* __restrict__ gamma, const float* __restrict__ beta,
    float* __restrict__ Z, float* __restrict__ Zn)
{
    const int r0 = blockIdx.x * 8;
    const int c  = threadIdx.x;

    float acc[8];
#pragma unroll
    for (int r = 0; r < 8; ++r) {
        const size_t i = (size_t)(r0 + r) * OD + c;
        acc[r] = Zp[i] + Zp[(size_t)TOT * OD + i];
    }

    __shared__ float s1[8][4], s2[8][4];
    const int lane = c & 63;
    const int wid  = c >> 6;
#pragma unroll
    for (int r = 0; r < 8; ++r) {
        float s = acc[r], q = acc[r] * acc[r];
#pragma unroll
        for (int off = 32; off > 0; off >>= 1) {
            s += __shfl_xor(s, off, 64);
            q += __shfl_xor(q, off, 64);
        }
        if (lane == 0) { s1[r][wid] = s; s2[r][wid] = q; }
    }
    __syncthreads();
#pragma unroll
    for (int r = 0; r < 8; ++r) {
        float s  = s1[r][0] + s1[r][1] + s1[r][2] + s1[r][3];
        float q  = s2[r][0] + s2[r][1] + s2[r][2] + s2[r][3];
        float mu = s * (1.f / OD);
        float var = q * (1.f / OD) - mu * mu;
        float inv = rsqrtf(var + LN_EPS);
        float z  = acc[r];
        float zn = (z - mu) * inv * gamma[c] + beta[c];
        Z [(size_t)(r0 + r) * OD + c] = z;
        Zn[(size_t)(r0 + r) * OD + c] = zn;
    }
}

// ============ K2 v3: T[k,i] = sum_j Zn[k,j]*P[i,j]*cos(2*pi*k/(i*256+j+2)) ============
// d-recurrence: d_k = P[i,j]*cos(2pi k/p) satisfies d_{k+2} = 2cos(2d)*d_k - d_{k-2};
// P folded into initial conditions -> inner loop = 1 acc-fma + 1 advance-fma per pair.
// Lane owns 32 k (kg = wave) x 2 adjacent i (z4 LDS read shared between the i's).
// Block 128 thr = 2 waves; tile 64k x 128i x 16j; grid (32,2,16) -> 2048 waves.
__global__ __launch_bounds__(128) void k2_t(
    const float* __restrict__ Zn, const float* __restrict__ P,
    short* __restrict__ Tp)
{
    const int k0 = blockIdx.x * 64;
    const int i0 = blockIdx.y * 128;
    const int j0 = blockIdx.z * JW;

    __shared__ float znT[JW][68];    // [j][k_local]: broadcast rows
    __shared__ float ptT[JW][132];   // [j][i_local]: lane pair -> ds_read_b64

    const int tid = threadIdx.x;
    {   // stage Zn^T: 64 rows x 16 j, threads split j in halves
        const int row = tid & 63;
        const int jh  = (tid >> 6) * 8;
        const float* zr = Zn + (size_t)(k0 + row) * OD + j0 + jh;
        float4 v0 = *(const float4*)(zr);
        float4 v1 = *(const float4*)(zr + 4);
        znT[jh + 0][row] = v0.x; znT[jh + 1][row] = v0.y;
        znT[jh + 2][row] = v0.z; znT[jh + 3][row] = v0.w;
        znT[jh + 4][row] = v1.x; znT[jh + 5][row] = v1.y;
        znT[jh + 6][row] = v1.z; znT[jh + 7][row] = v1.w;
        // stage P^T: 128 i rows x 16 j
        const float* pr = P + (size_t)(i0 + tid) * OD + j0;
        float4 p0 = *(const float4*)(pr);
        float4 p1 = *(const float4*)(pr + 4);
        float4 p2 = *(const float4*)(pr + 8);
        float4 p3 = *(const float4*)(pr + 12);
        ptT[ 0][tid] = p0.x; ptT[ 1][tid] = p0.y; ptT[ 2][tid] = p0.z; ptT[ 3][tid] = p0.w;
        ptT[ 4][tid] = p1.x; ptT[ 5][tid] = p1.y; ptT[ 6][tid] = p1.z; ptT[ 7][tid] = p1.w;
        ptT[ 8][tid] = p2.x; ptT[ 9][tid] = p2.y; ptT[10][tid] = p2.z; ptT[11][tid] = p2.w;
        ptT[12][tid] = p3.x; ptT[13][tid] = p3.y; ptT[14][tid] = p3.z; ptT[15][tid] = p3.w;
    }
    __syncthreads();

    const int kg = tid >> 6;              // wave = k-half
    const int l  = tid & 63;
    const int il = 2 * l;                 // local i pair
    const float kbase = (float)(k0 + kg * 32);
    const float pbA   = (float)((i0 + il) * OD + j0 + 2);     // exact (< 2^24)

    f32x2 accA[16], accB[16];
#pragma unroll
    for (int m = 0; m < 16; ++m) { accA[m] = (f32x2){0.f, 0.f}; accB[m] = (f32x2){0.f, 0.f}; }

    const float* zrow = &znT[0][kg * 32];

    for (int j = 0; j < JW; ++j) {
        f32x2 wp = *(const f32x2*)&ptT[j][il];    // {wA, wB} one b64
        // --- setup i = A ---
        const float pA  = pbA + (float)j;
        const float ipA = __builtin_amdgcn_rcpf(pA);
        const float aA  = __builtin_amdgcn_fractf(kbase * ipA);
        const float c0A = __builtin_amdgcn_cosf(aA);
        const float s0A = __builtin_amdgcn_sinf(aA);
        const float cdA = __builtin_amdgcn_cosf(ipA);
        const float sdA = __builtin_amdgcn_sinf(ipA);
        const float c1A = c0A * cdA - s0A * sdA;
        const float s1A = s0A * cdA + c0A * sdA;
        const float c2A = c1A * cdA - s1A * sdA;
        const float c3A = c2A * cdA - (s1A * cdA + c1A * sdA) * sdA;
        const float r2A = 2.f * (1.f - 2.f * sdA * sdA);
        f32x2 DA_p = {wp.x * c0A, wp.x * c1A};
        f32x2 DA_c = {wp.x * c2A, wp.x * c3A};
        const f32x2 RA = {r2A, r2A};
        // --- setup i = B (p + 256) ---
        const float pB  = pA + 256.f;
        const float ipB = __builtin_amdgcn_rcpf(pB);
        const float aB  = __builtin_amdgcn_fractf(kbase * ipB);
        const float c0B = __builtin_amdgcn_cosf(aB);
        const float s0B = __builtin_amdgcn_sinf(aB);
        const float cdB = __builtin_amdgcn_cosf(ipB);
        const float sdB = __builtin_amdgcn_sinf(ipB);
        const float c1B = c0B * cdB - s0B * sdB;
        const float s1B = s0B * cdB + c0B * sdB;
        const float c2B = c1B * cdB - s1B * sdB;
        const float c3B = c2B * cdB - (s1B * cdB + c1B * sdB) * sdB;
        const float r2B = 2.f * (1.f - 2.f * sdB * sdB);
        f32x2 DB_p = {wp.y * c0B, wp.y * c1B};
        f32x2 DB_c = {wp.y * c2B, wp.y * c3B};
        const f32x2 RB = {r2B, r2B};

        const float* zc = zrow + (size_t)j * 68;
#pragma unroll
        for (int m = 0; m < 8; ++m) {     // 8 x float4 = 32 k = 16 pairs
            float4 z4 = *(const float4*)(zc + 4 * m);
            f32x2 zlo = {z4.x, z4.y};
            f32x2 zhi = {z4.z, z4.w};
            accA[2 * m    ] += zlo * DA_p;
            accB[2 * m    ] += zlo * DB_p;
            f32x2 tA = RA * DA_c - DA_p;  DA_p = DA_c;  DA_c = tA;
            f32x2 tB = RB * DB_c - DB_p;  DB_p = DB_c;  DB_c = tB;
            accA[2 * m + 1] += zhi * DA_p;
            accB[2 * m + 1] += zhi * DB_p;
            tA = RA * DA_c - DA_p;  DA_p = DA_c;  DA_c = tA;
            tB = RB * DB_c - DB_p;  DB_p = DB_c;  DB_c = tB;
        }
    }

    short* Tpl = Tp + (size_t)blockIdx.z * (TOT * OD);
    const int ia = i0 + il;
    const int kb = k0 + kg * 32;
#pragma unroll
    for (int m = 0; m < 16; ++m) {
        *(uint*)(Tpl + (size_t)(kb + 2 * m    ) * OD + ia) = pack2(accA[m].x, accB[m].x);
        *(uint*)(Tpl + (size_t)(kb + 2 * m + 1) * OD + ia) = pack2(accA[m].y, accB[m].y);
    }
}

// ============ K2b: Wt[b][o][s] = bf16(Z + sum Tp) transposed ============
// 32x32 tiles -> 512 blocks (2 waves/SIMD).
__global__ __launch_bounds__(256) void k2b_w(
    const float* __restrict__ Z, const short* __restrict__ Tp,
    short* __restrict__ Wt)
{
    __shared__ float tl[32][36];
    const int kt0 = blockIdx.x * 32;    // global k = b*1024+s
    const int o0  = blockIdx.y * 32;
    const int tid = threadIdx.x;
    const int r   = tid >> 3;           // 0..31 (kt row)
    const int c4  = (tid & 7) * 4;      // 0..28 (o col)

    const size_t idx = (size_t)(kt0 + r) * OD + o0 + c4;
    float4 z = *(const float4*)(Z + idx);
#pragma unroll
    for (int p = 0; p < JSPL; ++p) {
        uint2 t = *(const uint2*)(Tp + (size_t)p * (TOT * OD) + idx);
        z.x += __uint_as_float(t.x << 16);
        z.y += __uint_as_float(t.x & 0xFFFF0000u);
        z.z += __uint_as_float(t.y << 16);
        z.w += __uint_as_float(t.y & 0xFFFF0000u);
    }
    *(float4*)&tl[r][c4] = z;
    __syncthreads();

    const int ol = tid >> 3;            // 0..31 (o row out)
    const int sc = (tid & 7) * 4;       // 0..28 (s col out)
    const int b  = kt0 >> 10;
    const int sb = kt0 & 1023;
    uint lo = pack2(tl[sc + 0][ol], tl[sc + 1][ol]);
    uint hi = pack2(tl[sc + 2][ol], tl[sc + 3][ol]);
    *(uint2*)(Wt + ((size_t)b * OD + o0 + ol) * SEQL + sb + sc) = make_uint2(lo, hi);
}

// ============ K3: Op[ksp][b] = ALt * Wt_b^T (s-chunk ksp) ============
__global__ __launch_bounds__(256, 4) void k3_mfma(
    const short* __restrict__ ALt, const short* __restrict__ Wt,
    float* __restrict__ Op)
{
    const int b   = blockIdx.z & 1;
    const int ksp = blockIdx.z >> 1;
    mfma_tile64(ALt, SEQL, Wt + (size_t)b * OD * SEQL, SEQL,
                Op + (size_t)ksp * (NB * TQ * OD) + (size_t)b * TQ * OD, OD,
                blockIdx.x * 64, blockIdx.y * 64, ksp * (SEQL / K3SPL), (SEQL / K3SPL) / 32);
}

// ============ K4: out = sum of 8 Op planes; write out_seq scalar ============
__global__ __launch_bounds__(256) void k4_comb(
    const float* __restrict__ Op, float* __restrict__ out, int out_size)
{
    const int m = blockIdx.x * 256 + threadIdx.x;   // float4 index
    const int N4 = (NB * TQ * OD) / 4;
    if (m < N4) {
        float4 a = ((const float4*)Op)[m];
#pragma unroll
        for (int p = 1; p < K3SPL; ++p) {
            float4 t = ((const float4*)(Op + (size_t)p * (NB * TQ * OD)))[m];
            a.x += t.x; a.y += t.y; a.z += t.z; a.w += t.w;
        }
        ((float4*)out)[m] = a;
    }
    if (m == 0 && out_size > NB * TQ * OD)
        out[NB * TQ * OD] = (float)TQ;   // second output: out_seq = 512
}

extern "C" void kernel_launch(void* const* d_in, const int* in_sizes, int n_in,
                              void* d_out, int out_size, void* d_ws, size_t ws_size,
                              hipStream_t stream)
{
    const float* x  = (const float*)d_in[0];
    const float* M  = (const float*)d_in[1];
    const float* P  = (const float*)d_in[2];
    const float* L  = (const float*)d_in[3];
    const float* g  = (const float*)d_in[4];
    const float* be = (const float*)d_in[5];
    float* out = (float*)d_out;

    float* ws_f = (float*)d_ws;
    float* Zp = ws_f;                               // 2 * TOT*OD f32
    float* Z  = Zp + 2 * (size_t)TOT * OD;          // TOT*OD f32
    float* Zn = Z  + (size_t)TOT * OD;              // TOT*OD f32
    float* Op = Zn + (size_t)TOT * OD;              // K3SPL * NB*TQ*OD f32
    short* xb  = (short*)(Op + (size_t)K3SPL * NB * TQ * OD);
    short* Mb  = xb  + (size_t)TOT * INDIM;
    short* ALt = Mb  + (size_t)OD * INDIM;
    short* Wt  = ALt + (size_t)TQ * SEQL;
    short* Tp  = Wt  + (size_t)NB * OD * SEQL;      // JSPL * TOT*OD bf16

    kcvt<<<1664, 256, 0, stream>>>(x, M, L, xb, Mb, ALt);
    k1_mfma<<<dim3(TOT / 64, OD / 64, 2), 256, 0, stream>>>(xb, Mb, Zp);
    k1b_ln<<<TOT / 8, 256, 0, stream>>>(Zp, g, be, Z, Zn);
    k2_t<<<dim3(TOT / 64, OD / 128, JSPL), 128, 0, stream>>>(Zn, P, Tp);
    k2b_w<<<dim3(TOT / 32, OD / 32), 256, 0, stream>>>(Z, Tp, Wt);
    k3_mfma<<<dim3(TQ / 64, OD / 64, NB * K3SPL), 256, 0, stream>>>(ALt, Wt, Op);
    k4_comb<<<(NB * TQ * OD / 4 + 255) / 256, 256, 0, stream>>>(Op, out, out_size);
}